// Round 13
// baseline (557.911 us; speedup 1.0000x reference)
//
#include <hip/hip_runtime.h>
#include <hip/hip_bf16.h>

#define CPE 8192   // edges per partition chunk

typedef short short8 __attribute__((ext_vector_type(8)));
typedef float f32x4 __attribute__((ext_vector_type(4)));
using u16 = unsigned short;

__device__ __forceinline__ float bf2f(u16 u) {
    return __uint_as_float(((unsigned)u) << 16);
}
__device__ __forceinline__ u16 f2bf(float f) {
    __hip_bfloat16 h = __float2bfloat16(f);   // RNE
    return *reinterpret_cast<u16*>(&h);
}

// ---------- batched weight convert: 6 fp32 arrays -> bf16 ----------
__global__ void k_wcvt6(const float* w0, const float* w1, const float* w2,
                        const float* w3, const float* w4, const float* w5,
                        u16* __restrict__ out,
                        int s0, int s1, int s2, int s3, int s4, int s5) {
    int i = blockIdx.x * blockDim.x + threadIdx.x;
    int b0 = s0, b1 = b0 + s1, b2 = b1 + s2, b3 = b2 + s3, b4 = b3 + s4, b5 = b4 + s5;
    if (i >= b5) return;
    const float* w;
    int o;
    if (i < b0) { w = w0; o = i; }
    else if (i < b1) { w = w1; o = i - b0; }
    else if (i < b2) { w = w2; o = i - b1; }
    else if (i < b3) { w = w3; o = i - b2; }
    else if (i < b4) { w = w4; o = i - b3; }
    else { w = w5; o = i - b4; }
    out[i] = f2bf(w[o]);
}

// ================= CSR build via coarse-bucket counting sort =================
// record u32 = ((dst & 255) << 16) | src   (requires N <= 65536)

__global__ void k_p1(const int* __restrict__ e0, const int* __restrict__ e1,
                     const int* __restrict__ e2, int* __restrict__ cnt,
                     int E, int nC, int NB) {
    __shared__ int h[256];
    int g = blockIdx.x / nC, c = blockIdx.x - g * nC;
    const int* dst = (g == 0 ? e0 : g == 1 ? e1 : e2) + E;
    for (int b = threadIdx.x; b < NB; b += 256) h[b] = 0;
    __syncthreads();
    int lo = c * CPE, hi = min(E, lo + CPE);
    for (int e = lo + threadIdx.x; e < hi; e += 256)
        atomicAdd(&h[dst[e] >> 8], 1);
    __syncthreads();
    for (int b = threadIdx.x; b < NB; b += 256)
        cnt[((long)g * NB + b) * nC + c] = h[b];
}

__global__ void k_p2a(const int* __restrict__ cnt, int* __restrict__ tot, int nC) {
    __shared__ int s[256];
    long gb = blockIdx.x;
    const int* row = cnt + gb * nC;
    int v = 0;
    for (int c = threadIdx.x; c < nC; c += 256) v += row[c];
    s[threadIdx.x] = v;
    __syncthreads();
    for (int o = 128; o > 0; o >>= 1) {
        if (threadIdx.x < o) s[threadIdx.x] += s[threadIdx.x + o];
        __syncthreads();
    }
    if (threadIdx.x == 0) tot[gb] = s[0];
}

__global__ void k_p2b(const int* __restrict__ tot, int* __restrict__ baseE,
                      int* __restrict__ rowptr, int E, int N, int NB) {
    __shared__ int s[256];
    int g = blockIdx.x, t = threadIdx.x;
    int v = (t < NB) ? tot[g * NB + t] : 0;
    s[t] = v;
    __syncthreads();
    for (int o = 1; o < 256; o <<= 1) {
        int a = (t >= o) ? s[t - o] : 0;
        __syncthreads();
        s[t] += a;
        __syncthreads();
    }
    if (t < NB) baseE[g * (NB + 1) + t] = s[t] - v;
    if (t == 0) {
        baseE[g * (NB + 1) + NB] = E;
        rowptr[(long)g * (N + 1) + N] = E;
    }
}

__global__ void k_p2c(const int* __restrict__ cnt, const int* __restrict__ baseE,
                      int* __restrict__ ofs, int nC, int NB) {
    __shared__ int s[256];
    long gb = blockIdx.x;
    int g = (int)(gb / NB), b = (int)(gb - (long)g * NB);
    int t = threadIdx.x;
    int v = (t < nC) ? cnt[gb * nC + t] : 0;
    s[t] = v;
    __syncthreads();
    for (int o = 1; o < 256; o <<= 1) {
        int a = (t >= o) ? s[t - o] : 0;
        __syncthreads();
        s[t] += a;
        __syncthreads();
    }
    if (t < nC) ofs[gb * nC + t] = baseE[g * (NB + 1) + b] + s[t] - v;
}

__global__ void k_p3(const int* __restrict__ e0, const int* __restrict__ e1,
                     const int* __restrict__ e2, const int* __restrict__ ofs,
                     unsigned* __restrict__ part, int E, int nC, int NB) {
    __shared__ int lbase[256];
    __shared__ int lcur[256];
    int g = blockIdx.x / nC, c = blockIdx.x - g * nC;
    const int* eg = (g == 0 ? e0 : g == 1 ? e1 : e2);
    const int* src = eg;
    const int* dst = eg + E;
    for (int b = threadIdx.x; b < NB; b += 256) {
        lbase[b] = ofs[((long)g * NB + b) * nC + c];
        lcur[b] = 0;
    }
    __syncthreads();
    int lo = c * CPE, hi = min(E, lo + CPE);
    unsigned* pg = part + (long)g * E;
    for (int e = lo + threadIdx.x; e < hi; e += 256) {
        int d = dst[e];
        int b = d >> 8;
        int pos = lbase[b] + atomicAdd(&lcur[b], 1);
        pg[pos] = ((unsigned)(d & 255) << 16) | (unsigned)src[e];
    }
}

__global__ void k_p4(const unsigned* __restrict__ part, const int* __restrict__ baseE,
                     int* __restrict__ rowptr, int* __restrict__ srcs,
                     int E, int N, int NB) {
    __shared__ int h[256];
    __shared__ int s[256];
    __shared__ int cur[256];
    int g = blockIdx.x / NB, b = blockIdx.x - g * NB;
    int n0 = b << 8;
    int nn = min(256, N - n0);
    int lo = baseE[g * (NB + 1) + b], hi = baseE[g * (NB + 1) + b + 1];
    int t = threadIdx.x;
    h[t] = 0;
    __syncthreads();
    const unsigned* pg = part + (long)g * E;
    for (int i = lo + t; i < hi; i += 256)
        atomicAdd(&h[pg[i] >> 16], 1);
    __syncthreads();
    int v = h[t];
    s[t] = v;
    __syncthreads();
    for (int o = 1; o < 256; o <<= 1) {
        int a = (t >= o) ? s[t - o] : 0;
        __syncthreads();
        s[t] += a;
        __syncthreads();
    }
    int excl = lo + s[t] - v;
    if (t < nn) rowptr[(long)g * (N + 1) + n0 + t] = excl;
    cur[t] = excl;
    __syncthreads();
    int* sg = srcs + (long)g * E;
    for (int i = lo + t; i < hi; i += 256) {
        unsigned r = pg[i];
        int pos = atomicAdd(&cur[r >> 16], 1);
        sg[pos] = (int)(r & 0xFFFFu);
    }
}

// ---------- generic MFMA GEMM core (used by L2/L3; Cin inlined constant) ----------
template <bool ABF, bool BN_IN, bool RELU_OUT, bool BF16_OUT>
__device__ __forceinline__ void gemm_body(const void* X, const float* stats,
                                          const u16* __restrict__ Wb,
                                          const float* __restrict__ bias,
                                          void* Yv, int MT, int Cin, int SH,
                                          int wl, int l) {
    int mt = wl >> SH;
    if (mt >= MT) return;
    int CG = 1 << SH;
    int COUT = CG * 64;
    int cg = wl & (CG - 1);
    int lm = l & 15, lh = l >> 4;
    int kb = lh * 8;

    const float* xrf = nullptr;
    const u16* xrb = nullptr;
    if (ABF) xrb = (const u16*)X + (long)(mt * 16 + lm) * Cin + kb;
    else     xrf = (const float*)X + (long)(mt * 16 + lm) * Cin + kb;
    const u16* wp[4];
#pragma unroll
    for (int t = 0; t < 4; ++t)
        wp[t] = Wb + (long)(cg * 64 + t * 16 + lm) * Cin + kb;
    const float* scp = nullptr;
    const float* shp = nullptr;
    if (BN_IN) {
        scp = stats + 2 * Cin + kb;
        shp = stats + 3 * Cin + kb;
    }

    f32x4 acc[4];
#pragma unroll
    for (int t = 0; t < 4; ++t) acc[t] = (f32x4){0.f, 0.f, 0.f, 0.f};

    for (int k0 = 0; k0 < Cin; k0 += 32) {
        short8 a;
        if (ABF) {
            short8 raw = *reinterpret_cast<const short8*>(xrb);
            if (BN_IN) {
#pragma unroll
                for (int j = 0; j < 8; ++j) {
                    float x = bf2f((u16)raw[j]);
                    x = fmaxf(fmaf(x, scp[j], shp[j]), 0.f);
                    a[j] = (short)f2bf(x);
                }
                scp += 32; shp += 32;
            } else {
                a = raw;
            }
            xrb += 32;
        } else {
            float4 x0 = *reinterpret_cast<const float4*>(xrf);
            float4 x1 = *reinterpret_cast<const float4*>(xrf + 4);
            a[0] = (short)f2bf(x0.x); a[1] = (short)f2bf(x0.y);
            a[2] = (short)f2bf(x0.z); a[3] = (short)f2bf(x0.w);
            a[4] = (short)f2bf(x1.x); a[5] = (short)f2bf(x1.y);
            a[6] = (short)f2bf(x1.z); a[7] = (short)f2bf(x1.w);
            xrf += 32;
        }
#pragma unroll
        for (int t = 0; t < 4; ++t) {
            short8 b = *reinterpret_cast<const short8*>(wp[t]);
            acc[t] = __builtin_amdgcn_mfma_f32_16x16x32_bf16(a, b, acc[t], 0, 0, 0);
            wp[t] += 32;
        }
    }

    int nb = mt * 16 + lh * 4;
#pragma unroll
    for (int t = 0; t < 4; ++t) {
        int col = cg * 64 + t * 16 + lm;
        float bi = bias[col];
#pragma unroll
        for (int r = 0; r < 4; ++r) {
            float v = acc[t][r] + bi;
            if (RELU_OUT) v = fmaxf(v, 0.f);
            if (BF16_OUT)
                ((u16*)Yv)[(long)(nb + r) * COUT + col] = f2bf(v);
            else
                ((float*)Yv)[(long)(nb + r) * COUT + col] = v;
        }
    }
}

// ---------- L1 GEMM v4: W-stationary, 256-row M-loop, dbuf LDS A, swizzled ----------
// Block = 256 thr (4 waves). W [128][CIN] bf16 staged once to LDS (swizzled).
// A staged in 4 sub-tiles of 64 rows, double-buffered; k-loop is pure LDS+MFMA.
template <int CIN>
__device__ __forceinline__ void gemmL1v4(const float* __restrict__ X,
                                         const u16* __restrict__ Wb,
                                         const float* __restrict__ bias,
                                         u16* __restrict__ Yb,
                                         int N, int m0, int tid, u16* S) {
    constexpr int LGC = (CIN == 256) ? 8 : 7;
    constexpr int ABUF = 64 * CIN;
    constexpr int WITER = (128 * CIN) / (256 * 8);
    constexpr int AITER = (64 * CIN) / (256 * 4);
    u16* Ws = S;
    u16* As = S + 128 * CIN;

    // ---- stage W (swizzled: byte ^= (row&7)<<4) ----
#pragma unroll
    for (int i = 0; i < WITER; ++i) {
        int e = (i * 256 + tid) * 8;
        int wr = e >> LGC;
        int wc = e & (CIN - 1);
        short8 v = *reinterpret_cast<const short8*>(Wb + e);
        int byte = (((wr << LGC) + wc) * 2) ^ ((wr & 7) << 4);
        *reinterpret_cast<short8*>(reinterpret_cast<char*>(Ws) + byte) = v;
    }

    // ---- stage A sub-tile 0 ----
    float4 r[AITER];
#pragma unroll
    for (int i = 0; i < AITER; ++i) {
        int f = i * 1024 + tid * 4;
        int row = f >> LGC, col = f & (CIN - 1);
        int gr = m0 + row;
        r[i] = (gr < N) ? *reinterpret_cast<const float4*>(X + (long)gr * CIN + col)
                        : make_float4(0.f, 0.f, 0.f, 0.f);
    }
#pragma unroll
    for (int i = 0; i < AITER; ++i) {
        int f = i * 1024 + tid * 4;
        int row = f >> LGC, col = f & (CIN - 1);
        int byte = (((row << LGC) + col) * 2) ^ ((row & 7) << 4);
        ushort4 b = make_ushort4(f2bf(r[i].x), f2bf(r[i].y), f2bf(r[i].z), f2bf(r[i].w));
        *reinterpret_cast<ushort4*>(reinterpret_cast<char*>(As) + byte) = b;
    }
    __syncthreads();

    int w = tid >> 6, l = tid & 63;
    int lm = l & 15, lh = l >> 4;
    int kb = lh * 8;
    int lr = (w << 4) + lm;

#pragma unroll
    for (int s = 0; s < 4; ++s) {
        u16* buf = As + (s & 1) * ABUF;
        // early-issue next sub-tile global loads (T14)
        if (s < 3) {
#pragma unroll
            for (int i = 0; i < AITER; ++i) {
                int f = i * 1024 + tid * 4;
                int row = f >> LGC, col = f & (CIN - 1);
                int gr = m0 + (s + 1) * 64 + row;
                r[i] = (gr < N) ? *reinterpret_cast<const float4*>(X + (long)gr * CIN + col)
                                : make_float4(0.f, 0.f, 0.f, 0.f);
            }
        }
        // compute: pure LDS + MFMA
        f32x4 acc[8];
#pragma unroll
        for (int t = 0; t < 8; ++t) acc[t] = (f32x4){0.f, 0.f, 0.f, 0.f};
#pragma unroll
        for (int k0 = 0; k0 < CIN; k0 += 32) {
            int abyte = (((lr << LGC) + k0 + kb) * 2) ^ ((lr & 7) << 4);
            short8 a = *reinterpret_cast<const short8*>(reinterpret_cast<char*>(buf) + abyte);
#pragma unroll
            for (int t = 0; t < 8; ++t) {
                int wr = (t << 4) + lm;
                int bbyte = (((wr << LGC) + k0 + kb) * 2) ^ ((wr & 7) << 4);
                short8 b = *reinterpret_cast<const short8*>(reinterpret_cast<char*>(Ws) + bbyte);
                acc[t] = __builtin_amdgcn_mfma_f32_16x16x32_bf16(a, b, acc[t], 0, 0, 0);
            }
        }
        // store C
        int nb = m0 + s * 64 + (w << 4) + lh * 4;
#pragma unroll
        for (int t = 0; t < 8; ++t) {
            int col = (t << 4) + lm;
            float bi = bias[col];
#pragma unroll
            for (int rr = 0; rr < 4; ++rr)
                if (nb + rr < N)
                    Yb[(long)(nb + rr) * 128 + col] = f2bf(acc[t][rr] + bi);
        }
        // late ds_write of next sub-tile into the other buffer
        if (s < 3) {
            u16* nbuf = As + ((s + 1) & 1) * ABUF;
#pragma unroll
            for (int i = 0; i < AITER; ++i) {
                int f = i * 1024 + tid * 4;
                int row = f >> LGC, col = f & (CIN - 1);
                int byte = (((row << LGC) + col) * 2) ^ ((row & 7) << 4);
                ushort4 b = make_ushort4(f2bf(r[i].x), f2bf(r[i].y), f2bf(r[i].z), f2bf(r[i].w));
                *reinterpret_cast<ushort4*>(reinterpret_cast<char*>(nbuf) + byte) = b;
            }
        }
        __syncthreads();
    }
}

__global__ __launch_bounds__(256) void k_gemmL1(
        const float* x0, const float* x1, const float* x2,
        const u16* w0, const u16* w1, const u16* w2,
        const float* b0, const float* b1, const float* b2,
        u16* Yb, int N, int B1) {
    __shared__ __align__(16) u16 S[128 * 256 + 2 * 64 * 256];   // 128 KB
    int g = blockIdx.x / B1;
    int m0 = (blockIdx.x - g * B1) * 256;
    int tid = threadIdx.x;
    if (g == 0)
        gemmL1v4<256>(x0, w0, b0, Yb, N, m0, tid, S);
    else if (g == 1)
        gemmL1v4<128>(x1, w1, b1, Yb + (long)N * 128, N, m0, tid, S);
    else
        gemmL1v4<256>(x2, w2, b2, Yb + (long)N * 256, N, m0, tid, S);
}

// L2: 3 graphs, A bf16 + BN_IN, shared weights, CG=1 (Cout 64), bf16 out
// output stride between graphs is N*64 (COUT=64) to match k_aggb3<64>.
__global__ __launch_bounds__(256) void k_gemmL2(
        const u16* Hb, const float* ST, const u16* wext, const float* bext,
        u16* Yb, int MT, int N, int B2) {
    int g = blockIdx.x / B2;
    int wl = (blockIdx.x - g * B2) * 4 + (threadIdx.x >> 6);
    gemm_body<true, true, false, true>(Hb + (long)g * N * 128, ST + g * 512, wext,
                                       bext, Yb + (long)g * N * 64, MT, 128, 0,
                                       wl, threadIdx.x & 63);
}

// L3: 2 graphs, A bf16, fp32 relu out; g0: CG=4 Cout256 -> f0, g1: CG=2 Cout128 -> f1
__global__ __launch_bounds__(256) void k_gemmL3(
        const u16* h3, const u16* wr0, const u16* wr1,
        const float* br0, const float* br1,
        float* f0, float* f1, int MT, int N, int B0) {
    int b = blockIdx.x;
    int g = (b < B0) ? 0 : 1;
    int wl = (g == 0 ? b : b - B0) * 4 + (threadIdx.x >> 6);
    if (g == 0)
        gemm_body<true, false, true, false>(h3, nullptr, wr0, br0, f0, MT, 64, 2,
                                            wl, threadIdx.x & 63);
    else
        gemm_body<true, false, true, false>(h3 + (long)N * 64, nullptr, wr1, br1,
                                            f1, MT, 64, 1, wl, threadIdx.x & 63);
}

// ---------- batched aggregation: out[n] = in[n] + sum_{e} in[src[e]] (bf16 in/out, fp32 acc) ----------
template <int CH>  // 128 or 64
__global__ void k_aggb3(const u16* __restrict__ in, const int* __restrict__ rp,
                        const int* __restrict__ sr, u16* __restrict__ outb,
                        int N, int E, int BPG) {
    int g = blockIdx.x / BPG;
    int bb = blockIdx.x - g * BPG;
    int l = threadIdx.x & 63;
    int ll = l & 31;
    int n = (bb << 3) + ((threadIdx.x >> 6) << 1) + (l >> 5);
    if (n >= N) return;
    const int* rowptr = rp + (long)g * (N + 1);
    const int* srcs = sr + (long)g * E;
    int p = rowptr[n], p1 = rowptr[n + 1];
    if constexpr (CH == 128) {
        const ushort4* Yp = reinterpret_cast<const ushort4*>(in + (long)g * N * 128) + ll;
        ushort4 a = Yp[(long)n << 5];
        float s0 = bf2f(a.x), s1 = bf2f(a.y), s2 = bf2f(a.z), s3 = bf2f(a.w);
        while (p + 8 <= p1) {
            ushort4 r[8];
#pragma unroll
            for (int j = 0; j < 8; ++j) r[j] = Yp[(long)srcs[p + j] << 5];
#pragma unroll
            for (int j = 0; j < 8; ++j) {
                s0 += bf2f(r[j].x); s1 += bf2f(r[j].y);
                s2 += bf2f(r[j].z); s3 += bf2f(r[j].w);
            }
            p += 8;
        }
        while (p < p1) {
            ushort4 r = Yp[(long)srcs[p] << 5];
            s0 += bf2f(r.x); s1 += bf2f(r.y); s2 += bf2f(r.z); s3 += bf2f(r.w);
            ++p;
        }
        ushort4 o = make_ushort4(f2bf(s0), f2bf(s1), f2bf(s2), f2bf(s3));
        (reinterpret_cast<ushort4*>(outb + (long)g * N * 128) + ll)[(long)n << 5] = o;
    } else {
        const unsigned* Yp = reinterpret_cast<const unsigned*>(in + (long)g * N * 64) + ll;
        unsigned a = Yp[(long)n << 5];
        float s0 = bf2f((u16)a), s1 = bf2f((u16)(a >> 16));
        while (p + 8 <= p1) {
            unsigned r[8];
#pragma unroll
            for (int j = 0; j < 8; ++j) r[j] = Yp[(long)srcs[p + j] << 5];
#pragma unroll
            for (int j = 0; j < 8; ++j) {
                s0 += bf2f((u16)r[j]);
                s1 += bf2f((u16)(r[j] >> 16));
            }
            p += 8;
        }
        while (p < p1) {
            unsigned r = Yp[(long)srcs[p] << 5];
            s0 += bf2f((u16)r);
            s1 += bf2f((u16)(r >> 16));
            ++p;
        }
        unsigned o = (unsigned)f2bf(s0) | ((unsigned)f2bf(s1) << 16);
        (reinterpret_cast<unsigned*>(outb + (long)g * N * 64) + ll)[(long)n << 5] = o;
    }
}

// ---------- BN stats (bf16 input), two-stage deterministic, batched ----------
template <int C>
__global__ void k_bnstats1(const u16* __restrict__ h, float* __restrict__ parts,
                           int N, int PSTRIDE) {
    constexpr int RPB = 256 / C;
    constexpr int LGC = (C == 128) ? 7 : 6;
    __shared__ float ts[256], ts2[256];
    int g = blockIdx.x >> 8;
    int blk = blockIdx.x & 255;
    const u16* hg = h + (long)g * N * C;
    float* pg = parts + (long)g * PSTRIDE;
    int tid = threadIdx.x;
    int c = tid & (C - 1);
    float s = 0.f, s2 = 0.f;
    for (int n = blk * RPB + (tid >> LGC); n < N; n += 256 * RPB) {
        float v = bf2f(hg[((long)n << LGC) + c]);
        s += v;
        s2 = fmaf(v, v, s2);
    }
    ts[tid] = s;
    ts2[tid] = s2;
    __syncthreads();
    if (tid < C) {
#pragma unroll
        for (int i = 1; i < RPB; ++i) {
            s += ts[tid + i * C];
            s2 += ts2[tid + i * C];
        }
        pg[blk * 2 * C + tid] = s;
        pg[blk * 2 * C + C + tid] = s2;
    }
}

template <int C>
__global__ void k_bnstats2(const float* __restrict__ parts,
                           const float* g0, const float* g1, const float* g2,
                           const float* b0, const float* b1, const float* b2,
                           float* __restrict__ ST, float invN, int PSTRIDE) {
    int g = blockIdx.x;
    const float* gam = g == 0 ? g0 : (g == 1 ? g1 : g2);
    const float* bet = g == 0 ? b0 : (g == 1 ? b1 : b2);
    const float* pg = parts + (long)g * PSTRIDE;
    float* st = ST + g * 4 * C;
    int c = threadIdx.x;
    float s = 0.f, s2 = 0.f;
    for (int b = 0; b < 256; ++b) {
        s += pg[b * 2 * C + c];
        s2 += pg[b * 2 * C + C + c];
    }
    float m = s * invN;
    float v = s2 * invN - m * m;
    float sc = gam[c] * rsqrtf(v + 1e-5f);
    st[2 * C + c] = sc;
    st[3 * C + c] = bet[c] - m * sc;
}

// ---------- batched BN apply (bf16 in, fp32 out + bf16 copy for g<2) ----------
__global__ void k_bnapply3(const u16* __restrict__ h2b, const float* __restrict__ ST2,
                           float* __restrict__ out, u16* __restrict__ obb,
                           int N, int BPG) {
    int g = blockIdx.x / BPG;
    int idx = (blockIdx.x - g * BPG) * 256 + threadIdx.x;
    if (idx >= N * 16) return;
    int n = idx >> 4;
    int c4 = (idx & 15) << 2;
    const u16* hg = h2b + (long)g * N * 64;
    const float* st = ST2 + g * 256;
    ushort4 hv = *reinterpret_cast<const ushort4*>(hg + ((long)n << 6) + c4);
    const float4 sc = *reinterpret_cast<const float4*>(st + 128 + c4);
    const float4 sh = *reinterpret_cast<const float4*>(st + 192 + c4);
    float4 o;
    o.x = fmaxf(fmaf(bf2f(hv.x), sc.x, sh.x), 0.f);
    o.y = fmaxf(fmaf(bf2f(hv.y), sc.y, sh.y), 0.f);
    o.z = fmaxf(fmaf(bf2f(hv.z), sc.z, sh.z), 0.f);
    o.w = fmaxf(fmaf(bf2f(hv.w), sc.w, sh.w), 0.f);
    // g0 -> o_h0 (out + N*64), g1 -> o_h1 (out + 2N*64), g2(s) -> o_hs (out)
    float* yb = (g == 0) ? out + (long)N * 64 : (g == 1) ? out + (long)N * 128 : out;
    *reinterpret_cast<float4*>(yb + ((long)n << 6) + c4) = o;
    if (g < 2) {
        ushort4 ob = make_ushort4(f2bf(o.x), f2bf(o.y), f2bf(o.z), f2bf(o.w));
        *reinterpret_cast<ushort4*>(obb + (long)g * N * 64 + ((long)n << 6) + c4) = ob;
    }
}

static inline int cdiv(long a, int b) { return (int)((a + b - 1) / b); }

extern "C" void kernel_launch(void* const* d_in, const int* in_sizes, int n_in,
                              void* d_out, int out_size, void* d_ws, size_t ws_size,
                              hipStream_t stream) {
    const float* ft0 = (const float*)d_in[0];
    const float* ft1 = (const float*)d_in[1];
    const float* fs  = (const float*)d_in[2];
    const int* et0 = (const int*)d_in[3];
    const int* et1 = (const int*)d_in[4];
    const int* es  = (const int*)d_in[5];
    const float* aT0_W = (const float*)d_in[6];
    const float* aT0_b = (const float*)d_in[7];
    const float* aT0_g = (const float*)d_in[8];
    const float* aT0_be = (const float*)d_in[9];
    const float* aT1_W = (const float*)d_in[10];
    const float* aT1_b = (const float*)d_in[11];
    const float* aT1_g = (const float*)d_in[12];
    const float* aT1_be = (const float*)d_in[13];
    const float* aS_W = (const float*)d_in[14];
    const float* aS_b = (const float*)d_in[15];
    const float* aS_g = (const float*)d_in[16];
    const float* aS_be = (const float*)d_in[17];
    const float* ext_W = (const float*)d_in[18];
    const float* ext_b = (const float*)d_in[19];
    const float* ext_g = (const float*)d_in[20];
    const float* ext_be = (const float*)d_in[21];
    const float* rT0_W = (const float*)d_in[22];
    const float* rT0_b = (const float*)d_in[23];
    const float* rT1_W = (const float*)d_in[24];
    const float* rT1_b = (const float*)d_in[25];

    const int N = in_sizes[0] / 256;
    const int E = in_sizes[3] / 2;
    const int NB = cdiv(N, 256);
    const int nC = cdiv(E, CPE);
    const int MT = N / 16;

    float* out = (float*)d_out;
    float* o_f0 = out + (long)N * 192;      // [N,256]
    float* o_f1 = out + (long)N * 448;      // [N,128]

    // workspace
    char* p = (char*)d_ws;
    auto align16 = [&]() { p = (char*)(((uintptr_t)p + 15) & ~(uintptr_t)15); };
    u16* Yb  = (u16*)p;        p += (size_t)3 * N * 128 * 2;   // L1/L2 gemm outputs
    u16* Hb  = (u16*)p;        p += (size_t)3 * N * 128 * 2;   // L1 pre-BN agg (bf16)
    u16* h2b = (u16*)p;        p += (size_t)3 * N * 64 * 2;    // L2 pre-BN agg / L3 agg
    u16* obb = (u16*)p;        p += (size_t)2 * N * 64 * 2;    // bf16 o_h0/o_h1
    int* rp   = (int*)p;       p += (size_t)3 * (N + 1) * 4;
    int* sr   = (int*)p;       p += (size_t)3 * E * 4;
    unsigned* part = (unsigned*)p; p += (size_t)3 * E * 4;
    int* cnt  = (int*)p;       p += (size_t)3 * NB * nC * 4;
    int* ofs  = (int*)p;       p += (size_t)3 * NB * nC * 4;
    int* tot  = (int*)p;       p += (size_t)3 * NB * 4;
    int* baseE = (int*)p;      p += (size_t)3 * (NB + 1) * 4;
    align16();
    u16* WBF = (u16*)p;        p += (size_t)(256*128 + 128*128 + 256*128 + 128*64 + 64*256 + 64*128) * 2;
    align16();
    float* ST1 = (float*)p;    p += (size_t)3 * 512 * 4;
    float* ST2 = (float*)p;    p += (size_t)3 * 256 * 4;
    float* PARTS = (float*)p;  p += (size_t)3 * 256 * 256 * 4;

    u16* aT0b = WBF;
    u16* aT1b = aT0b + 256 * 128;
    u16* aSb  = aT1b + 128 * 128;
    u16* extb = aSb + 256 * 128;
    u16* rT0b = extb + 128 * 64;
    u16* rT1b = rT0b + 64 * 256;

    // ---- CSR build ----
    k_p1<<<3 * nC, 256, 0, stream>>>(et0, et1, es, cnt, E, nC, NB);
    k_p2a<<<3 * NB, 256, 0, stream>>>(cnt, tot, nC);
    k_p2b<<<3, 256, 0, stream>>>(tot, baseE, rp, E, N, NB);
    k_p2c<<<3 * NB, 256, 0, stream>>>(cnt, baseE, ofs, nC, NB);
    k_p3<<<3 * nC, 256, 0, stream>>>(et0, et1, es, ofs, part, E, nC, NB);
    k_p4<<<3 * NB, 256, 0, stream>>>(part, baseE, rp, sr, E, N, NB);

    // ---- weight converts (one launch) ----
    {
        int tot_w = 256*128 + 128*128 + 256*128 + 128*64 + 64*256 + 64*128;
        k_wcvt6<<<cdiv(tot_w, 256), 256, 0, stream>>>(
            aT0_W, aT1_W, aS_W, ext_W, rT0_W, rT1_W, WBF,
            256*128, 128*128, 256*128, 128*64, 64*256, 64*128);
    }

    const int B1 = cdiv(N, 256);     // L1: one block per 256-row M-tile
    const int B2 = cdiv(MT, 4);
    const int BPG = N / 8;           // agg blocks per graph (N % 8 == 0)
    const int BPA = cdiv((long)N * 16, 256);  // bnapply blocks per graph

    // ---- layer 1 ----
    k_gemmL1<<<3 * B1, 256, 0, stream>>>(ft0, ft1, fs, aT0b, aT1b, aSb,
                                         aT0_b, aT1_b, aS_b, Yb, N, B1);
    k_aggb3<128><<<3 * BPG, 256, 0, stream>>>(Yb, rp, sr, Hb, N, E, BPG);
    k_bnstats1<128><<<3 * 256, 256, 0, stream>>>(Hb, PARTS, N, 256 * 256);
    k_bnstats2<128><<<3, 128, 0, stream>>>(PARTS, aT0_g, aT1_g, aS_g,
                                           aT0_be, aT1_be, aS_be, ST1, 1.0f / N, 256 * 256);

    // ---- layer 2 ----
    k_gemmL2<<<3 * B2, 256, 0, stream>>>(Hb, ST1, extb, ext_b, Yb, MT, N, B2);
    k_aggb3<64><<<3 * BPG, 256, 0, stream>>>(Yb, rp, sr, h2b, N, E, BPG);
    k_bnstats1<64><<<3 * 256, 256, 0, stream>>>(h2b, PARTS, N, 256 * 128);
    k_bnstats2<64><<<3, 64, 0, stream>>>(PARTS, ext_g, ext_g, ext_g,
                                         ext_be, ext_be, ext_be, ST2, 1.0f / N, 256 * 128);
    k_bnapply3<<<3 * BPA, 256, 0, stream>>>(h2b, ST2, out, obb, N, BPA);

    // ---- layer 3 ----
    k_aggb3<64><<<2 * BPG, 256, 0, stream>>>(obb, rp, sr, h2b, N, E, BPG);
    k_gemmL3<<<MT + cdiv((long)MT * 2, 4), 256, 0, stream>>>(
        h2b, rT0b, rT1b, rT0_b, rT1_b, o_f0, o_f1, MT, N, MT);
}

// Round 14
// 532.628 us; speedup vs baseline: 1.0475x; 1.0475x over previous
//
#include <hip/hip_runtime.h>
#include <hip/hip_bf16.h>

#define CPE 8192   // edges per partition chunk

typedef short short8 __attribute__((ext_vector_type(8)));
typedef float f32x4 __attribute__((ext_vector_type(4)));
using u16 = unsigned short;

__device__ __forceinline__ float bf2f(u16 u) {
    return __uint_as_float(((unsigned)u) << 16);
}
__device__ __forceinline__ u16 f2bf(float f) {
    __hip_bfloat16 h = __float2bfloat16(f);   // RNE
    return *reinterpret_cast<u16*>(&h);
}

// ---------- batched weight convert: 6 fp32 arrays -> bf16 ----------
__global__ void k_wcvt6(const float* w0, const float* w1, const float* w2,
                        const float* w3, const float* w4, const float* w5,
                        u16* __restrict__ out,
                        int s0, int s1, int s2, int s3, int s4, int s5) {
    int i = blockIdx.x * blockDim.x + threadIdx.x;
    int b0 = s0, b1 = b0 + s1, b2 = b1 + s2, b3 = b2 + s3, b4 = b3 + s4, b5 = b4 + s5;
    if (i >= b5) return;
    const float* w;
    int o;
    if (i < b0) { w = w0; o = i; }
    else if (i < b1) { w = w1; o = i - b0; }
    else if (i < b2) { w = w2; o = i - b1; }
    else if (i < b3) { w = w3; o = i - b2; }
    else if (i < b4) { w = w4; o = i - b3; }
    else { w = w5; o = i - b4; }
    out[i] = f2bf(w[o]);
}

// ================= CSR build via coarse-bucket counting sort =================
// record u32 = ((dst & 255) << 16) | src   (requires N <= 65536)

__global__ void k_p1(const int* __restrict__ e0, const int* __restrict__ e1,
                     const int* __restrict__ e2, int* __restrict__ cnt,
                     int E, int nC, int NB) {
    __shared__ int h[256];
    int g = blockIdx.x / nC, c = blockIdx.x - g * nC;
    const int* dst = (g == 0 ? e0 : g == 1 ? e1 : e2) + E;
    for (int b = threadIdx.x; b < NB; b += 256) h[b] = 0;
    __syncthreads();
    int lo = c * CPE, hi = min(E, lo + CPE);
    for (int e = lo + threadIdx.x; e < hi; e += 256)
        atomicAdd(&h[dst[e] >> 8], 1);
    __syncthreads();
    for (int b = threadIdx.x; b < NB; b += 256)
        cnt[((long)g * NB + b) * nC + c] = h[b];
}

__global__ void k_p2a(const int* __restrict__ cnt, int* __restrict__ tot, int nC) {
    __shared__ int s[256];
    long gb = blockIdx.x;
    const int* row = cnt + gb * nC;
    int v = 0;
    for (int c = threadIdx.x; c < nC; c += 256) v += row[c];
    s[threadIdx.x] = v;
    __syncthreads();
    for (int o = 128; o > 0; o >>= 1) {
        if (threadIdx.x < o) s[threadIdx.x] += s[threadIdx.x + o];
        __syncthreads();
    }
    if (threadIdx.x == 0) tot[gb] = s[0];
}

__global__ void k_p2b(const int* __restrict__ tot, int* __restrict__ baseE,
                      int* __restrict__ rowptr, int E, int N, int NB) {
    __shared__ int s[256];
    int g = blockIdx.x, t = threadIdx.x;
    int v = (t < NB) ? tot[g * NB + t] : 0;
    s[t] = v;
    __syncthreads();
    for (int o = 1; o < 256; o <<= 1) {
        int a = (t >= o) ? s[t - o] : 0;
        __syncthreads();
        s[t] += a;
        __syncthreads();
    }
    if (t < NB) baseE[g * (NB + 1) + t] = s[t] - v;
    if (t == 0) {
        baseE[g * (NB + 1) + NB] = E;
        rowptr[(long)g * (N + 1) + N] = E;
    }
}

__global__ void k_p2c(const int* __restrict__ cnt, const int* __restrict__ baseE,
                      int* __restrict__ ofs, int nC, int NB) {
    __shared__ int s[256];
    long gb = blockIdx.x;
    int g = (int)(gb / NB), b = (int)(gb - (long)g * NB);
    int t = threadIdx.x;
    int v = (t < nC) ? cnt[gb * nC + t] : 0;
    s[t] = v;
    __syncthreads();
    for (int o = 1; o < 256; o <<= 1) {
        int a = (t >= o) ? s[t - o] : 0;
        __syncthreads();
        s[t] += a;
        __syncthreads();
    }
    if (t < nC) ofs[gb * nC + t] = baseE[g * (NB + 1) + b] + s[t] - v;
}

__global__ void k_p3(const int* __restrict__ e0, const int* __restrict__ e1,
                     const int* __restrict__ e2, const int* __restrict__ ofs,
                     unsigned* __restrict__ part, int E, int nC, int NB) {
    __shared__ int lbase[256];
    __shared__ int lcur[256];
    int g = blockIdx.x / nC, c = blockIdx.x - g * nC;
    const int* eg = (g == 0 ? e0 : g == 1 ? e1 : e2);
    const int* src = eg;
    const int* dst = eg + E;
    for (int b = threadIdx.x; b < NB; b += 256) {
        lbase[b] = ofs[((long)g * NB + b) * nC + c];
        lcur[b] = 0;
    }
    __syncthreads();
    int lo = c * CPE, hi = min(E, lo + CPE);
    unsigned* pg = part + (long)g * E;
    for (int e = lo + threadIdx.x; e < hi; e += 256) {
        int d = dst[e];
        int b = d >> 8;
        int pos = lbase[b] + atomicAdd(&lcur[b], 1);
        pg[pos] = ((unsigned)(d & 255) << 16) | (unsigned)src[e];
    }
}

__global__ void k_p4(const unsigned* __restrict__ part, const int* __restrict__ baseE,
                     int* __restrict__ rowptr, int* __restrict__ srcs,
                     int E, int N, int NB) {
    __shared__ int h[256];
    __shared__ int s[256];
    __shared__ int cur[256];
    int g = blockIdx.x / NB, b = blockIdx.x - g * NB;
    int n0 = b << 8;
    int nn = min(256, N - n0);
    int lo = baseE[g * (NB + 1) + b], hi = baseE[g * (NB + 1) + b + 1];
    int t = threadIdx.x;
    h[t] = 0;
    __syncthreads();
    const unsigned* pg = part + (long)g * E;
    for (int i = lo + t; i < hi; i += 256)
        atomicAdd(&h[pg[i] >> 16], 1);
    __syncthreads();
    int v = h[t];
    s[t] = v;
    __syncthreads();
    for (int o = 1; o < 256; o <<= 1) {
        int a = (t >= o) ? s[t - o] : 0;
        __syncthreads();
        s[t] += a;
        __syncthreads();
    }
    int excl = lo + s[t] - v;
    if (t < nn) rowptr[(long)g * (N + 1) + n0 + t] = excl;
    cur[t] = excl;
    __syncthreads();
    int* sg = srcs + (long)g * E;
    for (int i = lo + t; i < hi; i += 256) {
        unsigned r = pg[i];
        int pos = atomicAdd(&cur[r >> 16], 1);
        sg[pos] = (int)(r & 0xFFFFu);
    }
}

// ---------- generic MFMA GEMM core (used by L2/L3; Cin inlined constant) ----------
template <bool ABF, bool BN_IN, bool RELU_OUT, bool BF16_OUT>
__device__ __forceinline__ void gemm_body(const void* X, const float* stats,
                                          const u16* __restrict__ Wb,
                                          const float* __restrict__ bias,
                                          void* Yv, int MT, int Cin, int SH,
                                          int wl, int l) {
    int mt = wl >> SH;
    if (mt >= MT) return;
    int CG = 1 << SH;
    int COUT = CG * 64;
    int cg = wl & (CG - 1);
    int lm = l & 15, lh = l >> 4;
    int kb = lh * 8;

    const float* xrf = nullptr;
    const u16* xrb = nullptr;
    if (ABF) xrb = (const u16*)X + (long)(mt * 16 + lm) * Cin + kb;
    else     xrf = (const float*)X + (long)(mt * 16 + lm) * Cin + kb;
    const u16* wp[4];
#pragma unroll
    for (int t = 0; t < 4; ++t)
        wp[t] = Wb + (long)(cg * 64 + t * 16 + lm) * Cin + kb;
    const float* scp = nullptr;
    const float* shp = nullptr;
    if (BN_IN) {
        scp = stats + 2 * Cin + kb;
        shp = stats + 3 * Cin + kb;
    }

    f32x4 acc[4];
#pragma unroll
    for (int t = 0; t < 4; ++t) acc[t] = (f32x4){0.f, 0.f, 0.f, 0.f};

    for (int k0 = 0; k0 < Cin; k0 += 32) {
        short8 a;
        if (ABF) {
            short8 raw = *reinterpret_cast<const short8*>(xrb);
            if (BN_IN) {
#pragma unroll
                for (int j = 0; j < 8; ++j) {
                    float x = bf2f((u16)raw[j]);
                    x = fmaxf(fmaf(x, scp[j], shp[j]), 0.f);
                    a[j] = (short)f2bf(x);
                }
                scp += 32; shp += 32;
            } else {
                a = raw;
            }
            xrb += 32;
        } else {
            float4 x0 = *reinterpret_cast<const float4*>(xrf);
            float4 x1 = *reinterpret_cast<const float4*>(xrf + 4);
            a[0] = (short)f2bf(x0.x); a[1] = (short)f2bf(x0.y);
            a[2] = (short)f2bf(x0.z); a[3] = (short)f2bf(x0.w);
            a[4] = (short)f2bf(x1.x); a[5] = (short)f2bf(x1.y);
            a[6] = (short)f2bf(x1.z); a[7] = (short)f2bf(x1.w);
            xrf += 32;
        }
#pragma unroll
        for (int t = 0; t < 4; ++t) {
            short8 b = *reinterpret_cast<const short8*>(wp[t]);
            acc[t] = __builtin_amdgcn_mfma_f32_16x16x32_bf16(a, b, acc[t], 0, 0, 0);
            wp[t] += 32;
        }
    }

    int nb = mt * 16 + lh * 4;
#pragma unroll
    for (int t = 0; t < 4; ++t) {
        int col = cg * 64 + t * 16 + lm;
        float bi = bias[col];
#pragma unroll
        for (int r = 0; r < 4; ++r) {
            float v = acc[t][r] + bi;
            if (RELU_OUT) v = fmaxf(v, 0.f);
            if (BF16_OUT)
                ((u16*)Yv)[(long)(nb + r) * COUT + col] = f2bf(v);
            else
                ((float*)Yv)[(long)(nb + r) * COUT + col] = v;
        }
    }
}

// ---------- L1 GEMM v5: K-split W-stationary, 48 KB LDS, pure-LDS k-loop ----------
// Block = 256 thr (4 waves), 256-row M-tile as 4 sub-tiles of 64 rows.
// Per (sub-tile, k-half): stage W-half [128][128] bf16 + A [64][128] bf16 (both
// XOR-swizzled byte ^= (row&7)<<4), then 4 k-steps x 8 MFMA from LDS only.
template <int CIN>
__device__ __forceinline__ void gemmL1v5(const float* __restrict__ X,
                                         const u16* __restrict__ Wb,
                                         const float* __restrict__ bias,
                                         u16* __restrict__ Yb,
                                         int N, int m0, int tid, u16* S) {
    constexpr int KH = CIN / 128;   // 2 or 1
    u16* Ws = S;                    // [128][128] bf16, 32 KB
    u16* As = S + 128 * 128;        // [64][128] bf16, 16 KB
    int w = tid >> 6, l = tid & 63;
    int lm = l & 15, lh = l >> 4;
    int kb = lh * 8;
    int lr = (w << 4) + lm;

#pragma unroll
    for (int s = 0; s < 4; ++s) {
        f32x4 acc[8];
#pragma unroll
        for (int t = 0; t < 8; ++t) acc[t] = (f32x4){0.f, 0.f, 0.f, 0.f};

#pragma unroll
        for (int kh = 0; kh < KH; ++kh) {
            // stage W half (L2-hot): 128x128 bf16, 8 x short8 per thread
#pragma unroll
            for (int i = 0; i < 8; ++i) {
                int e = (i * 256 + tid) * 8;
                int wr = e >> 7, wc = e & 127;
                short8 v = *reinterpret_cast<const short8*>(Wb + (long)wr * CIN + kh * 128 + wc);
                int byte = (((wr << 7) + wc) * 2) ^ ((wr & 7) << 4);
                *reinterpret_cast<short8*>(reinterpret_cast<char*>(Ws) + byte) = v;
            }
            // stage A sub-tile: 64 rows x 128 f32 -> bf16, coalesced float4 reads
#pragma unroll
            for (int i = 0; i < 8; ++i) {
                int f = i * 1024 + tid * 4;
                int row = f >> 7, col = f & 127;
                int gr = m0 + s * 64 + row;
                float4 x = make_float4(0.f, 0.f, 0.f, 0.f);
                if (gr < N) x = *reinterpret_cast<const float4*>(X + (long)gr * CIN + kh * 128 + col);
                ushort4 b = make_ushort4(f2bf(x.x), f2bf(x.y), f2bf(x.z), f2bf(x.w));
                int byte = (((row << 7) + col) * 2) ^ ((row & 7) << 4);
                *reinterpret_cast<ushort4*>(reinterpret_cast<char*>(As) + byte) = b;
            }
            __syncthreads();
            // compute: pure LDS + MFMA
#pragma unroll
            for (int k0 = 0; k0 < 128; k0 += 32) {
                int abyte = (((lr << 7) + k0 + kb) * 2) ^ ((lr & 7) << 4);
                short8 a = *reinterpret_cast<const short8*>(reinterpret_cast<char*>(As) + abyte);
#pragma unroll
                for (int t = 0; t < 8; ++t) {
                    int wr2 = (t << 4) + lm;
                    int bbyte = (((wr2 << 7) + k0 + kb) * 2) ^ ((wr2 & 7) << 4);
                    short8 b = *reinterpret_cast<const short8*>(reinterpret_cast<char*>(Ws) + bbyte);
                    acc[t] = __builtin_amdgcn_mfma_f32_16x16x32_bf16(a, b, acc[t], 0, 0, 0);
                }
            }
            __syncthreads();   // LDS reused next kh / next s
        }
        // store C sub-tile
        int nb = m0 + s * 64 + (w << 4) + lh * 4;
#pragma unroll
        for (int t = 0; t < 8; ++t) {
            int col = (t << 4) + lm;
            float bi = bias[col];
#pragma unroll
            for (int rr = 0; rr < 4; ++rr)
                if (nb + rr < N)
                    Yb[(long)(nb + rr) * 128 + col] = f2bf(acc[t][rr] + bi);
        }
    }
}

__global__ __launch_bounds__(256) void k_gemmL1(
        const float* x0, const float* x1, const float* x2,
        const u16* w0, const u16* w1, const u16* w2,
        const float* b0, const float* b1, const float* b2,
        u16* Yb, int N, int B1) {
    __shared__ __align__(16) u16 S[128 * 128 + 64 * 128];   // 48 KB
    int g = blockIdx.x / B1;
    int m0 = (blockIdx.x - g * B1) * 256;
    int tid = threadIdx.x;
    if (g == 0)
        gemmL1v5<256>(x0, w0, b0, Yb, N, m0, tid, S);
    else if (g == 1)
        gemmL1v5<128>(x1, w1, b1, Yb + (long)N * 128, N, m0, tid, S);
    else
        gemmL1v5<256>(x2, w2, b2, Yb + (long)N * 256, N, m0, tid, S);
}

// L2: 3 graphs, A bf16 + BN_IN, shared weights, CG=1 (Cout 64), bf16 out
// output stride between graphs is N*64 (COUT=64) to match k_aggb3<64>.
__global__ __launch_bounds__(256) void k_gemmL2(
        const u16* Hb, const float* ST, const u16* wext, const float* bext,
        u16* Yb, int MT, int N, int B2) {
    int g = blockIdx.x / B2;
    int wl = (blockIdx.x - g * B2) * 4 + (threadIdx.x >> 6);
    gemm_body<true, true, false, true>(Hb + (long)g * N * 128, ST + g * 512, wext,
                                       bext, Yb + (long)g * N * 64, MT, 128, 0,
                                       wl, threadIdx.x & 63);
}

// L3: 2 graphs, A bf16, fp32 relu out; g0: CG=4 Cout256 -> f0, g1: CG=2 Cout128 -> f1
__global__ __launch_bounds__(256) void k_gemmL3(
        const u16* h3, const u16* wr0, const u16* wr1,
        const float* br0, const float* br1,
        float* f0, float* f1, int MT, int N, int B0) {
    int b = blockIdx.x;
    int g = (b < B0) ? 0 : 1;
    int wl = (g == 0 ? b : b - B0) * 4 + (threadIdx.x >> 6);
    if (g == 0)
        gemm_body<true, false, true, false>(h3, nullptr, wr0, br0, f0, MT, 64, 2,
                                            wl, threadIdx.x & 63);
    else
        gemm_body<true, false, true, false>(h3 + (long)N * 64, nullptr, wr1, br1,
                                            f1, MT, 64, 1, wl, threadIdx.x & 63);
}

// ---------- batched aggregation: out[n] = in[n] + sum_{e} in[src[e]] (bf16 in/out, fp32 acc) ----------
template <int CH>  // 128 or 64
__global__ void k_aggb3(const u16* __restrict__ in, const int* __restrict__ rp,
                        const int* __restrict__ sr, u16* __restrict__ outb,
                        int N, int E, int BPG) {
    int g = blockIdx.x / BPG;
    int bb = blockIdx.x - g * BPG;
    int l = threadIdx.x & 63;
    int ll = l & 31;
    int n = (bb << 3) + ((threadIdx.x >> 6) << 1) + (l >> 5);
    if (n >= N) return;
    const int* rowptr = rp + (long)g * (N + 1);
    const int* srcs = sr + (long)g * E;
    int p = rowptr[n], p1 = rowptr[n + 1];
    if constexpr (CH == 128) {
        const ushort4* Yp = reinterpret_cast<const ushort4*>(in + (long)g * N * 128) + ll;
        ushort4 a = Yp[(long)n << 5];
        float s0 = bf2f(a.x), s1 = bf2f(a.y), s2 = bf2f(a.z), s3 = bf2f(a.w);
        while (p + 8 <= p1) {
            ushort4 r[8];
#pragma unroll
            for (int j = 0; j < 8; ++j) r[j] = Yp[(long)srcs[p + j] << 5];
#pragma unroll
            for (int j = 0; j < 8; ++j) {
                s0 += bf2f(r[j].x); s1 += bf2f(r[j].y);
                s2 += bf2f(r[j].z); s3 += bf2f(r[j].w);
            }
            p += 8;
        }
        while (p < p1) {
            ushort4 r = Yp[(long)srcs[p] << 5];
            s0 += bf2f(r.x); s1 += bf2f(r.y); s2 += bf2f(r.z); s3 += bf2f(r.w);
            ++p;
        }
        ushort4 o = make_ushort4(f2bf(s0), f2bf(s1), f2bf(s2), f2bf(s3));
        (reinterpret_cast<ushort4*>(outb + (long)g * N * 128) + ll)[(long)n << 5] = o;
    } else {
        const unsigned* Yp = reinterpret_cast<const unsigned*>(in + (long)g * N * 64) + ll;
        unsigned a = Yp[(long)n << 5];
        float s0 = bf2f((u16)a), s1 = bf2f((u16)(a >> 16));
        while (p + 8 <= p1) {
            unsigned r[8];
#pragma unroll
            for (int j = 0; j < 8; ++j) r[j] = Yp[(long)srcs[p + j] << 5];
#pragma unroll
            for (int j = 0; j < 8; ++j) {
                s0 += bf2f((u16)r[j]);
                s1 += bf2f((u16)(r[j] >> 16));
            }
            p += 8;
        }
        while (p < p1) {
            unsigned r = Yp[(long)srcs[p] << 5];
            s0 += bf2f((u16)r);
            s1 += bf2f((u16)(r >> 16));
            ++p;
        }
        unsigned o = (unsigned)f2bf(s0) | ((unsigned)f2bf(s1) << 16);
        (reinterpret_cast<unsigned*>(outb + (long)g * N * 64) + ll)[(long)n << 5] = o;
    }
}

// ---------- BN stats (bf16 input), two-stage deterministic, batched ----------
template <int C>
__global__ void k_bnstats1(const u16* __restrict__ h, float* __restrict__ parts,
                           int N, int PSTRIDE) {
    constexpr int RPB = 256 / C;
    constexpr int LGC = (C == 128) ? 7 : 6;
    __shared__ float ts[256], ts2[256];
    int g = blockIdx.x >> 8;
    int blk = blockIdx.x & 255;
    const u16* hg = h + (long)g * N * C;
    float* pg = parts + (long)g * PSTRIDE;
    int tid = threadIdx.x;
    int c = tid & (C - 1);
    float s = 0.f, s2 = 0.f;
    for (int n = blk * RPB + (tid >> LGC); n < N; n += 256 * RPB) {
        float v = bf2f(hg[((long)n << LGC) + c]);
        s += v;
        s2 = fmaf(v, v, s2);
    }
    ts[tid] = s;
    ts2[tid] = s2;
    __syncthreads();
    if (tid < C) {
#pragma unroll
        for (int i = 1; i < RPB; ++i) {
            s += ts[tid + i * C];
            s2 += ts2[tid + i * C];
        }
        pg[blk * 2 * C + tid] = s;
        pg[blk * 2 * C + C + tid] = s2;
    }
}

template <int C>
__global__ void k_bnstats2(const float* __restrict__ parts,
                           const float* g0, const float* g1, const float* g2,
                           const float* b0, const float* b1, const float* b2,
                           float* __restrict__ ST, float invN, int PSTRIDE) {
    int g = blockIdx.x;
    const float* gam = g == 0 ? g0 : (g == 1 ? g1 : g2);
    const float* bet = g == 0 ? b0 : (g == 1 ? b1 : b2);
    const float* pg = parts + (long)g * PSTRIDE;
    float* st = ST + g * 4 * C;
    int c = threadIdx.x;
    float s = 0.f, s2 = 0.f;
    for (int b = 0; b < 256; ++b) {
        s += pg[b * 2 * C + c];
        s2 += pg[b * 2 * C + C + c];
    }
    float m = s * invN;
    float v = s2 * invN - m * m;
    float sc = gam[c] * rsqrtf(v + 1e-5f);
    st[2 * C + c] = sc;
    st[3 * C + c] = bet[c] - m * sc;
}

// ---------- batched BN apply (bf16 in, fp32 out + bf16 copy for g<2) ----------
__global__ void k_bnapply3(const u16* __restrict__ h2b, const float* __restrict__ ST2,
                           float* __restrict__ out, u16* __restrict__ obb,
                           int N, int BPG) {
    int g = blockIdx.x / BPG;
    int idx = (blockIdx.x - g * BPG) * 256 + threadIdx.x;
    if (idx >= N * 16) return;
    int n = idx >> 4;
    int c4 = (idx & 15) << 2;
    const u16* hg = h2b + (long)g * N * 64;
    const float* st = ST2 + g * 256;
    ushort4 hv = *reinterpret_cast<const ushort4*>(hg + ((long)n << 6) + c4);
    const float4 sc = *reinterpret_cast<const float4*>(st + 128 + c4);
    const float4 sh = *reinterpret_cast<const float4*>(st + 192 + c4);
    float4 o;
    o.x = fmaxf(fmaf(bf2f(hv.x), sc.x, sh.x), 0.f);
    o.y = fmaxf(fmaf(bf2f(hv.y), sc.y, sh.y), 0.f);
    o.z = fmaxf(fmaf(bf2f(hv.z), sc.z, sh.z), 0.f);
    o.w = fmaxf(fmaf(bf2f(hv.w), sc.w, sh.w), 0.f);
    // g0 -> o_h0 (out + N*64), g1 -> o_h1 (out + 2N*64), g2(s) -> o_hs (out)
    float* yb = (g == 0) ? out + (long)N * 64 : (g == 1) ? out + (long)N * 128 : out;
    *reinterpret_cast<float4*>(yb + ((long)n << 6) + c4) = o;
    if (g < 2) {
        ushort4 ob = make_ushort4(f2bf(o.x), f2bf(o.y), f2bf(o.z), f2bf(o.w));
        *reinterpret_cast<ushort4*>(obb + (long)g * N * 64 + ((long)n << 6) + c4) = ob;
    }
}

static inline int cdiv(long a, int b) { return (int)((a + b - 1) / b); }

extern "C" void kernel_launch(void* const* d_in, const int* in_sizes, int n_in,
                              void* d_out, int out_size, void* d_ws, size_t ws_size,
                              hipStream_t stream) {
    const float* ft0 = (const float*)d_in[0];
    const float* ft1 = (const float*)d_in[1];
    const float* fs  = (const float*)d_in[2];
    const int* et0 = (const int*)d_in[3];
    const int* et1 = (const int*)d_in[4];
    const int* es  = (const int*)d_in[5];
    const float* aT0_W = (const float*)d_in[6];
    const float* aT0_b = (const float*)d_in[7];
    const float* aT0_g = (const float*)d_in[8];
    const float* aT0_be = (const float*)d_in[9];
    const float* aT1_W = (const float*)d_in[10];
    const float* aT1_b = (const float*)d_in[11];
    const float* aT1_g = (const float*)d_in[12];
    const float* aT1_be = (const float*)d_in[13];
    const float* aS_W = (const float*)d_in[14];
    const float* aS_b = (const float*)d_in[15];
    const float* aS_g = (const float*)d_in[16];
    const float* aS_be = (const float*)d_in[17];
    const float* ext_W = (const float*)d_in[18];
    const float* ext_b = (const float*)d_in[19];
    const float* ext_g = (const float*)d_in[20];
    const float* ext_be = (const float*)d_in[21];
    const float* rT0_W = (const float*)d_in[22];
    const float* rT0_b = (const float*)d_in[23];
    const float* rT1_W = (const float*)d_in[24];
    const float* rT1_b = (const float*)d_in[25];

    const int N = in_sizes[0] / 256;
    const int E = in_sizes[3] / 2;
    const int NB = cdiv(N, 256);
    const int nC = cdiv(E, CPE);
    const int MT = N / 16;

    float* out = (float*)d_out;
    float* o_f0 = out + (long)N * 192;      // [N,256]
    float* o_f1 = out + (long)N * 448;      // [N,128]

    // workspace
    char* p = (char*)d_ws;
    auto align16 = [&]() { p = (char*)(((uintptr_t)p + 15) & ~(uintptr_t)15); };
    u16* Yb  = (u16*)p;        p += (size_t)3 * N * 128 * 2;   // L1/L2 gemm outputs
    u16* Hb  = (u16*)p;        p += (size_t)3 * N * 128 * 2;   // L1 pre-BN agg (bf16)
    u16* h2b = (u16*)p;        p += (size_t)3 * N * 64 * 2;    // L2 pre-BN agg / L3 agg
    u16* obb = (u16*)p;        p += (size_t)2 * N * 64 * 2;    // bf16 o_h0/o_h1
    int* rp   = (int*)p;       p += (size_t)3 * (N + 1) * 4;
    int* sr   = (int*)p;       p += (size_t)3 * E * 4;
    unsigned* part = (unsigned*)p; p += (size_t)3 * E * 4;
    int* cnt  = (int*)p;       p += (size_t)3 * NB * nC * 4;
    int* ofs  = (int*)p;       p += (size_t)3 * NB * nC * 4;
    int* tot  = (int*)p;       p += (size_t)3 * NB * 4;
    int* baseE = (int*)p;      p += (size_t)3 * (NB + 1) * 4;
    align16();
    u16* WBF = (u16*)p;        p += (size_t)(256*128 + 128*128 + 256*128 + 128*64 + 64*256 + 64*128) * 2;
    align16();
    float* ST1 = (float*)p;    p += (size_t)3 * 512 * 4;
    float* ST2 = (float*)p;    p += (size_t)3 * 256 * 4;
    float* PARTS = (float*)p;  p += (size_t)3 * 256 * 256 * 4;

    u16* aT0b = WBF;
    u16* aT1b = aT0b + 256 * 128;
    u16* aSb  = aT1b + 128 * 128;
    u16* extb = aSb + 256 * 128;
    u16* rT0b = extb + 128 * 64;
    u16* rT1b = rT0b + 64 * 256;

    // ---- CSR build ----
    k_p1<<<3 * nC, 256, 0, stream>>>(et0, et1, es, cnt, E, nC, NB);
    k_p2a<<<3 * NB, 256, 0, stream>>>(cnt, tot, nC);
    k_p2b<<<3, 256, 0, stream>>>(tot, baseE, rp, E, N, NB);
    k_p2c<<<3 * NB, 256, 0, stream>>>(cnt, baseE, ofs, nC, NB);
    k_p3<<<3 * nC, 256, 0, stream>>>(et0, et1, es, ofs, part, E, nC, NB);
    k_p4<<<3 * NB, 256, 0, stream>>>(part, baseE, rp, sr, E, N, NB);

    // ---- weight converts (one launch) ----
    {
        int tot_w = 256*128 + 128*128 + 256*128 + 128*64 + 64*256 + 64*128;
        k_wcvt6<<<cdiv(tot_w, 256), 256, 0, stream>>>(
            aT0_W, aT1_W, aS_W, ext_W, rT0_W, rT1_W, WBF,
            256*128, 128*128, 256*128, 128*64, 64*256, 64*128);
    }

    const int B1 = cdiv(N, 256);     // L1: one block per 256-row M-tile
    const int B2 = cdiv(MT, 4);
    const int BPG = N / 8;           // agg blocks per graph (N % 8 == 0)
    const int BPA = cdiv((long)N * 16, 256);  // bnapply blocks per graph

    // ---- layer 1 ----
    k_gemmL1<<<3 * B1, 256, 0, stream>>>(ft0, ft1, fs, aT0b, aT1b, aSb,
                                         aT0_b, aT1_b, aS_b, Yb, N, B1);
    k_aggb3<128><<<3 * BPG, 256, 0, stream>>>(Yb, rp, sr, Hb, N, E, BPG);
    k_bnstats1<128><<<3 * 256, 256, 0, stream>>>(Hb, PARTS, N, 256 * 256);
    k_bnstats2<128><<<3, 128, 0, stream>>>(PARTS, aT0_g, aT1_g, aS_g,
                                           aT0_be, aT1_be, aS_be, ST1, 1.0f / N, 256 * 256);

    // ---- layer 2 ----
    k_gemmL2<<<3 * B2, 256, 0, stream>>>(Hb, ST1, extb, ext_b, Yb, MT, N, B2);
    k_aggb3<64><<<3 * BPG, 256, 0, stream>>>(Yb, rp, sr, h2b, N, E, BPG);
    k_bnstats1<64><<<3 * 256, 256, 0, stream>>>(h2b, PARTS, N, 256 * 128);
    k_bnstats2<64><<<3, 64, 0, stream>>>(PARTS, ext_g, ext_g, ext_g,
                                         ext_be, ext_be, ext_be, ST2, 1.0f / N, 256 * 128);
    k_bnapply3<<<3 * BPA, 256, 0, stream>>>(h2b, ST2, out, obb, N, BPA);

    // ---- layer 3 ----
    k_aggb3<64><<<2 * BPG, 256, 0, stream>>>(obb, rp, sr, h2b, N, E, BPG);
    k_gemmL3<<<MT + cdiv((long)MT * 2, 4), 256, 0, stream>>>(
        h2b, rT0b, rT1b, rT0_b, rT1_b, o_f0, o_f1, MT, N, MT);
}

// Round 15
// 484.631 us; speedup vs baseline: 1.1512x; 1.0990x over previous
//
#include <hip/hip_runtime.h>
#include <hip/hip_bf16.h>

#define CPE 8192   // edges per partition chunk

typedef short short8 __attribute__((ext_vector_type(8)));
typedef float f32x4 __attribute__((ext_vector_type(4)));
using u16 = unsigned short;

__device__ __forceinline__ float bf2f(u16 u) {
    return __uint_as_float(((unsigned)u) << 16);
}
__device__ __forceinline__ u16 f2bf(float f) {
    __hip_bfloat16 h = __float2bfloat16(f);   // RNE
    return *reinterpret_cast<u16*>(&h);
}

// ---------- batched weight convert: 6 fp32 arrays -> bf16 ----------
__global__ void k_wcvt6(const float* w0, const float* w1, const float* w2,
                        const float* w3, const float* w4, const float* w5,
                        u16* __restrict__ out,
                        int s0, int s1, int s2, int s3, int s4, int s5) {
    int i = blockIdx.x * blockDim.x + threadIdx.x;
    int b0 = s0, b1 = b0 + s1, b2 = b1 + s2, b3 = b2 + s3, b4 = b3 + s4, b5 = b4 + s5;
    if (i >= b5) return;
    const float* w;
    int o;
    if (i < b0) { w = w0; o = i; }
    else if (i < b1) { w = w1; o = i - b0; }
    else if (i < b2) { w = w2; o = i - b1; }
    else if (i < b3) { w = w3; o = i - b2; }
    else if (i < b4) { w = w4; o = i - b3; }
    else { w = w5; o = i - b4; }
    out[i] = f2bf(w[o]);
}

// ================= CSR build via coarse-bucket counting sort =================
// record u32 = ((dst & 255) << 16) | src   (requires N <= 65536)

__global__ void k_p1(const int* __restrict__ e0, const int* __restrict__ e1,
                     const int* __restrict__ e2, int* __restrict__ cnt,
                     int E, int nC, int NB) {
    __shared__ int h[256];
    int g = blockIdx.x / nC, c = blockIdx.x - g * nC;
    const int* dst = (g == 0 ? e0 : g == 1 ? e1 : e2) + E;
    for (int b = threadIdx.x; b < NB; b += 256) h[b] = 0;
    __syncthreads();
    int lo = c * CPE, hi = min(E, lo + CPE);
    for (int e = lo + threadIdx.x; e < hi; e += 256)
        atomicAdd(&h[dst[e] >> 8], 1);
    __syncthreads();
    for (int b = threadIdx.x; b < NB; b += 256)
        cnt[((long)g * NB + b) * nC + c] = h[b];
}

__global__ void k_p2a(const int* __restrict__ cnt, int* __restrict__ tot, int nC) {
    __shared__ int s[256];
    long gb = blockIdx.x;
    const int* row = cnt + gb * nC;
    int v = 0;
    for (int c = threadIdx.x; c < nC; c += 256) v += row[c];
    s[threadIdx.x] = v;
    __syncthreads();
    for (int o = 128; o > 0; o >>= 1) {
        if (threadIdx.x < o) s[threadIdx.x] += s[threadIdx.x + o];
        __syncthreads();
    }
    if (threadIdx.x == 0) tot[gb] = s[0];
}

__global__ void k_p2b(const int* __restrict__ tot, int* __restrict__ baseE,
                      int* __restrict__ rowptr, int E, int N, int NB) {
    __shared__ int s[256];
    int g = blockIdx.x, t = threadIdx.x;
    int v = (t < NB) ? tot[g * NB + t] : 0;
    s[t] = v;
    __syncthreads();
    for (int o = 1; o < 256; o <<= 1) {
        int a = (t >= o) ? s[t - o] : 0;
        __syncthreads();
        s[t] += a;
        __syncthreads();
    }
    if (t < NB) baseE[g * (NB + 1) + t] = s[t] - v;
    if (t == 0) {
        baseE[g * (NB + 1) + NB] = E;
        rowptr[(long)g * (N + 1) + N] = E;
    }
}

__global__ void k_p2c(const int* __restrict__ cnt, const int* __restrict__ baseE,
                      int* __restrict__ ofs, int nC, int NB) {
    __shared__ int s[256];
    long gb = blockIdx.x;
    int g = (int)(gb / NB), b = (int)(gb - (long)g * NB);
    int t = threadIdx.x;
    int v = (t < nC) ? cnt[gb * nC + t] : 0;
    s[t] = v;
    __syncthreads();
    for (int o = 1; o < 256; o <<= 1) {
        int a = (t >= o) ? s[t - o] : 0;
        __syncthreads();
        s[t] += a;
        __syncthreads();
    }
    if (t < nC) ofs[gb * nC + t] = baseE[g * (NB + 1) + b] + s[t] - v;
}

__global__ void k_p3(const int* __restrict__ e0, const int* __restrict__ e1,
                     const int* __restrict__ e2, const int* __restrict__ ofs,
                     unsigned* __restrict__ part, int E, int nC, int NB) {
    __shared__ int lbase[256];
    __shared__ int lcur[256];
    int g = blockIdx.x / nC, c = blockIdx.x - g * nC;
    const int* eg = (g == 0 ? e0 : g == 1 ? e1 : e2);
    const int* src = eg;
    const int* dst = eg + E;
    for (int b = threadIdx.x; b < NB; b += 256) {
        lbase[b] = ofs[((long)g * NB + b) * nC + c];
        lcur[b] = 0;
    }
    __syncthreads();
    int lo = c * CPE, hi = min(E, lo + CPE);
    unsigned* pg = part + (long)g * E;
    for (int e = lo + threadIdx.x; e < hi; e += 256) {
        int d = dst[e];
        int b = d >> 8;
        int pos = lbase[b] + atomicAdd(&lcur[b], 1);
        pg[pos] = ((unsigned)(d & 255) << 16) | (unsigned)src[e];
    }
}

__global__ void k_p4(const unsigned* __restrict__ part, const int* __restrict__ baseE,
                     int* __restrict__ rowptr, int* __restrict__ srcs,
                     int E, int N, int NB) {
    __shared__ int h[256];
    __shared__ int s[256];
    __shared__ int cur[256];
    int g = blockIdx.x / NB, b = blockIdx.x - g * NB;
    int n0 = b << 8;
    int nn = min(256, N - n0);
    int lo = baseE[g * (NB + 1) + b], hi = baseE[g * (NB + 1) + b + 1];
    int t = threadIdx.x;
    h[t] = 0;
    __syncthreads();
    const unsigned* pg = part + (long)g * E;
    for (int i = lo + t; i < hi; i += 256)
        atomicAdd(&h[pg[i] >> 16], 1);
    __syncthreads();
    int v = h[t];
    s[t] = v;
    __syncthreads();
    for (int o = 1; o < 256; o <<= 1) {
        int a = (t >= o) ? s[t - o] : 0;
        __syncthreads();
        s[t] += a;
        __syncthreads();
    }
    int excl = lo + s[t] - v;
    if (t < nn) rowptr[(long)g * (N + 1) + n0 + t] = excl;
    cur[t] = excl;
    __syncthreads();
    int* sg = srcs + (long)g * E;
    for (int i = lo + t; i < hi; i += 256) {
        unsigned r = pg[i];
        int pos = atomicAdd(&cur[r >> 16], 1);
        sg[pos] = (int)(r & 0xFFFFu);
    }
}

// ---------- generic MFMA GEMM core (used by L2/L3; 16 rows/wave) ----------
template <bool ABF, bool BN_IN, bool RELU_OUT, bool BF16_OUT>
__device__ __forceinline__ void gemm_body(const void* X, const float* stats,
                                          const u16* __restrict__ Wb,
                                          const float* __restrict__ bias,
                                          void* Yv, int MT, int Cin, int SH,
                                          int wl, int l) {
    int mt = wl >> SH;
    if (mt >= MT) return;
    int CG = 1 << SH;
    int COUT = CG * 64;
    int cg = wl & (CG - 1);
    int lm = l & 15, lh = l >> 4;
    int kb = lh * 8;

    const float* xrf = nullptr;
    const u16* xrb = nullptr;
    if (ABF) xrb = (const u16*)X + (long)(mt * 16 + lm) * Cin + kb;
    else     xrf = (const float*)X + (long)(mt * 16 + lm) * Cin + kb;
    const u16* wp[4];
#pragma unroll
    for (int t = 0; t < 4; ++t)
        wp[t] = Wb + (long)(cg * 64 + t * 16 + lm) * Cin + kb;
    const float* scp = nullptr;
    const float* shp = nullptr;
    if (BN_IN) {
        scp = stats + 2 * Cin + kb;
        shp = stats + 3 * Cin + kb;
    }

    f32x4 acc[4];
#pragma unroll
    for (int t = 0; t < 4; ++t) acc[t] = (f32x4){0.f, 0.f, 0.f, 0.f};

    for (int k0 = 0; k0 < Cin; k0 += 32) {
        short8 a;
        if (ABF) {
            short8 raw = *reinterpret_cast<const short8*>(xrb);
            if (BN_IN) {
#pragma unroll
                for (int j = 0; j < 8; ++j) {
                    float x = bf2f((u16)raw[j]);
                    x = fmaxf(fmaf(x, scp[j], shp[j]), 0.f);
                    a[j] = (short)f2bf(x);
                }
                scp += 32; shp += 32;
            } else {
                a = raw;
            }
            xrb += 32;
        } else {
            float4 x0 = *reinterpret_cast<const float4*>(xrf);
            float4 x1 = *reinterpret_cast<const float4*>(xrf + 4);
            a[0] = (short)f2bf(x0.x); a[1] = (short)f2bf(x0.y);
            a[2] = (short)f2bf(x0.z); a[3] = (short)f2bf(x0.w);
            a[4] = (short)f2bf(x1.x); a[5] = (short)f2bf(x1.y);
            a[6] = (short)f2bf(x1.z); a[7] = (short)f2bf(x1.w);
            xrf += 32;
        }
#pragma unroll
        for (int t = 0; t < 4; ++t) {
            short8 b = *reinterpret_cast<const short8*>(wp[t]);
            acc[t] = __builtin_amdgcn_mfma_f32_16x16x32_bf16(a, b, acc[t], 0, 0, 0);
            wp[t] += 32;
        }
    }

    int nb = mt * 16 + lh * 4;
#pragma unroll
    for (int t = 0; t < 4; ++t) {
        int col = cg * 64 + t * 16 + lm;
        float bi = bias[col];
#pragma unroll
        for (int r = 0; r < 4; ++r) {
            float v = acc[t][r] + bi;
            if (RELU_OUT) v = fmaxf(v, 0.f);
            if (BF16_OUT)
                ((u16*)Yv)[(long)(nb + r) * COUT + col] = f2bf(v);
            else
                ((float*)Yv)[(long)(nb + r) * COUT + col] = v;
        }
    }
}

// ---------- L1 GEMM m4: 64 rows x 64 cols per wave; B reused across 4 M-frags ----------
// Cuts B-traffic 4x vs 16-row waves (L3-BW theory). OOB rows: clamped loads, guarded stores.
__device__ __forceinline__ void gemmL1m4(const float* __restrict__ X,
                                         const u16* __restrict__ Wb,
                                         const float* __restrict__ bias,
                                         u16* __restrict__ Yb,
                                         int N, int Cin, int wl, int l) {
    int mt = wl >> 1;          // 64-row supertile
    int cg = wl & 1;           // 64-col half
    int m0 = mt * 64;
    if (m0 >= N) return;
    int lm = l & 15, lh = l >> 4;
    int kb = lh * 8;

    const u16* wp[4];
#pragma unroll
    for (int t = 0; t < 4; ++t)
        wp[t] = Wb + (long)(cg * 64 + t * 16 + lm) * Cin + kb;

    const float* xr[4];
#pragma unroll
    for (int mi = 0; mi < 4; ++mi) {
        int row = m0 + mi * 16 + lm;
        if (row >= N) row = N - 1;   // clamp: garbage lands only in unstored D rows
        xr[mi] = X + (long)row * Cin + kb;
    }

    f32x4 acc[4][4];
#pragma unroll
    for (int mi = 0; mi < 4; ++mi)
#pragma unroll
        for (int t = 0; t < 4; ++t) acc[mi][t] = (f32x4){0.f, 0.f, 0.f, 0.f};

    for (int k0 = 0; k0 < Cin; k0 += 32) {
        short8 b[4];
#pragma unroll
        for (int t = 0; t < 4; ++t) {
            b[t] = *reinterpret_cast<const short8*>(wp[t]);
            wp[t] += 32;
        }
        short8 a[4];
#pragma unroll
        for (int mi = 0; mi < 4; ++mi) {
            float4 x0 = *reinterpret_cast<const float4*>(xr[mi]);
            float4 x1 = *reinterpret_cast<const float4*>(xr[mi] + 4);
            xr[mi] += 32;
            a[mi][0] = (short)f2bf(x0.x); a[mi][1] = (short)f2bf(x0.y);
            a[mi][2] = (short)f2bf(x0.z); a[mi][3] = (short)f2bf(x0.w);
            a[mi][4] = (short)f2bf(x1.x); a[mi][5] = (short)f2bf(x1.y);
            a[mi][6] = (short)f2bf(x1.z); a[mi][7] = (short)f2bf(x1.w);
        }
#pragma unroll
        for (int mi = 0; mi < 4; ++mi)
#pragma unroll
            for (int t = 0; t < 4; ++t)
                acc[mi][t] = __builtin_amdgcn_mfma_f32_16x16x32_bf16(a[mi], b[t], acc[mi][t], 0, 0, 0);
    }

#pragma unroll
    for (int mi = 0; mi < 4; ++mi) {
        int nb = m0 + mi * 16 + lh * 4;
#pragma unroll
        for (int t = 0; t < 4; ++t) {
            int col = cg * 64 + t * 16 + lm;
            float bi = bias[col];
#pragma unroll
            for (int r = 0; r < 4; ++r) {
                int row = nb + r;
                if (row < N)
                    Yb[(long)row * 128 + col] = f2bf(acc[mi][t][r] + bi);
            }
        }
    }
}

__global__ __launch_bounds__(256) void k_gemmL1(
        const float* x0, const float* x1, const float* x2,
        const u16* w0, const u16* w1, const u16* w2,
        const float* b0, const float* b1, const float* b2,
        u16* Yb, int N, int B1) {
    int g = blockIdx.x / B1;
    int wl = (blockIdx.x - g * B1) * 4 + (threadIdx.x >> 6);
    int l = threadIdx.x & 63;
    const float* x = g == 0 ? x0 : (g == 1 ? x1 : x2);
    const u16* w = g == 0 ? w0 : (g == 1 ? w1 : w2);
    const float* b = g == 0 ? b0 : (g == 1 ? b1 : b2);
    int cin = (g == 1) ? 128 : 256;
    gemmL1m4(x, w, b, Yb + (long)g * N * 128, N, cin, wl, l);
}

// L2: 3 graphs, A bf16 + BN_IN, shared weights, CG=1 (Cout 64), bf16 out
// output stride between graphs is N*64 (COUT=64) to match k_aggb3<64>.
__global__ __launch_bounds__(256) void k_gemmL2(
        const u16* Hb, const float* ST, const u16* wext, const float* bext,
        u16* Yb, int MT, int N, int B2) {
    int g = blockIdx.x / B2;
    int wl = (blockIdx.x - g * B2) * 4 + (threadIdx.x >> 6);
    gemm_body<true, true, false, true>(Hb + (long)g * N * 128, ST + g * 512, wext,
                                       bext, Yb + (long)g * N * 64, MT, 128, 0,
                                       wl, threadIdx.x & 63);
}

// L3: 2 graphs, A bf16, fp32 relu out; g0: CG=4 Cout256 -> f0, g1: CG=2 Cout128 -> f1
__global__ __launch_bounds__(256) void k_gemmL3(
        const u16* h3, const u16* wr0, const u16* wr1,
        const float* br0, const float* br1,
        float* f0, float* f1, int MT, int N, int B0) {
    int b = blockIdx.x;
    int g = (b < B0) ? 0 : 1;
    int wl = (g == 0 ? b : b - B0) * 4 + (threadIdx.x >> 6);
    if (g == 0)
        gemm_body<true, false, true, false>(h3, nullptr, wr0, br0, f0, MT, 64, 2,
                                            wl, threadIdx.x & 63);
    else
        gemm_body<true, false, true, false>(h3 + (long)N * 64, nullptr, wr1, br1,
                                            f1, MT, 64, 1, wl, threadIdx.x & 63);
}

// ---------- batched aggregation: out[n] = in[n] + sum_{e} in[src[e]] (bf16 in/out, fp32 acc) ----------
template <int CH>  // 128 or 64
__global__ void k_aggb3(const u16* __restrict__ in, const int* __restrict__ rp,
                        const int* __restrict__ sr, u16* __restrict__ outb,
                        int N, int E, int BPG) {
    int g = blockIdx.x / BPG;
    int bb = blockIdx.x - g * BPG;
    int l = threadIdx.x & 63;
    int ll = l & 31;
    int n = (bb << 3) + ((threadIdx.x >> 6) << 1) + (l >> 5);
    if (n >= N) return;
    const int* rowptr = rp + (long)g * (N + 1);
    const int* srcs = sr + (long)g * E;
    int p = rowptr[n], p1 = rowptr[n + 1];
    if constexpr (CH == 128) {
        const ushort4* Yp = reinterpret_cast<const ushort4*>(in + (long)g * N * 128) + ll;
        ushort4 a = Yp[(long)n << 5];
        float s0 = bf2f(a.x), s1 = bf2f(a.y), s2 = bf2f(a.z), s3 = bf2f(a.w);
        while (p + 8 <= p1) {
            ushort4 r[8];
#pragma unroll
            for (int j = 0; j < 8; ++j) r[j] = Yp[(long)srcs[p + j] << 5];
#pragma unroll
            for (int j = 0; j < 8; ++j) {
                s0 += bf2f(r[j].x); s1 += bf2f(r[j].y);
                s2 += bf2f(r[j].z); s3 += bf2f(r[j].w);
            }
            p += 8;
        }
        while (p < p1) {
            ushort4 r = Yp[(long)srcs[p] << 5];
            s0 += bf2f(r.x); s1 += bf2f(r.y); s2 += bf2f(r.z); s3 += bf2f(r.w);
            ++p;
        }
        ushort4 o = make_ushort4(f2bf(s0), f2bf(s1), f2bf(s2), f2bf(s3));
        (reinterpret_cast<ushort4*>(outb + (long)g * N * 128) + ll)[(long)n << 5] = o;
    } else {
        const unsigned* Yp = reinterpret_cast<const unsigned*>(in + (long)g * N * 64) + ll;
        unsigned a = Yp[(long)n << 5];
        float s0 = bf2f((u16)a), s1 = bf2f((u16)(a >> 16));
        while (p + 8 <= p1) {
            unsigned r[8];
#pragma unroll
            for (int j = 0; j < 8; ++j) r[j] = Yp[(long)srcs[p + j] << 5];
#pragma unroll
            for (int j = 0; j < 8; ++j) {
                s0 += bf2f((u16)r[j]);
                s1 += bf2f((u16)(r[j] >> 16));
            }
            p += 8;
        }
        while (p < p1) {
            unsigned r = Yp[(long)srcs[p] << 5];
            s0 += bf2f((u16)r);
            s1 += bf2f((u16)(r >> 16));
            ++p;
        }
        unsigned o = (unsigned)f2bf(s0) | ((unsigned)f2bf(s1) << 16);
        (reinterpret_cast<unsigned*>(outb + (long)g * N * 64) + ll)[(long)n << 5] = o;
    }
}

// ---------- BN stats (bf16 input), two-stage deterministic, batched ----------
template <int C>
__global__ void k_bnstats1(const u16* __restrict__ h, float* __restrict__ parts,
                           int N, int PSTRIDE) {
    constexpr int RPB = 256 / C;
    constexpr int LGC = (C == 128) ? 7 : 6;
    __shared__ float ts[256], ts2[256];
    int g = blockIdx.x >> 8;
    int blk = blockIdx.x & 255;
    const u16* hg = h + (long)g * N * C;
    float* pg = parts + (long)g * PSTRIDE;
    int tid = threadIdx.x;
    int c = tid & (C - 1);
    float s = 0.f, s2 = 0.f;
    for (int n = blk * RPB + (tid >> LGC); n < N; n += 256 * RPB) {
        float v = bf2f(hg[((long)n << LGC) + c]);
        s += v;
        s2 = fmaf(v, v, s2);
    }
    ts[tid] = s;
    ts2[tid] = s2;
    __syncthreads();
    if (tid < C) {
#pragma unroll
        for (int i = 1; i < RPB; ++i) {
            s += ts[tid + i * C];
            s2 += ts2[tid + i * C];
        }
        pg[blk * 2 * C + tid] = s;
        pg[blk * 2 * C + C + tid] = s2;
    }
}

template <int C>
__global__ void k_bnstats2(const float* __restrict__ parts,
                           const float* g0, const float* g1, const float* g2,
                           const float* b0, const float* b1, const float* b2,
                           float* __restrict__ ST, float invN, int PSTRIDE) {
    int g = blockIdx.x;
    const float* gam = g == 0 ? g0 : (g == 1 ? g1 : g2);
    const float* bet = g == 0 ? b0 : (g == 1 ? b1 : b2);
    const float* pg = parts + (long)g * PSTRIDE;
    float* st = ST + g * 4 * C;
    int c = threadIdx.x;
    float s = 0.f, s2 = 0.f;
    for (int b = 0; b < 256; ++b) {
        s += pg[b * 2 * C + c];
        s2 += pg[b * 2 * C + C + c];
    }
    float m = s * invN;
    float v = s2 * invN - m * m;
    float sc = gam[c] * rsqrtf(v + 1e-5f);
    st[2 * C + c] = sc;
    st[3 * C + c] = bet[c] - m * sc;
}

// ---------- batched BN apply (bf16 in, fp32 out + bf16 copy for g<2) ----------
__global__ void k_bnapply3(const u16* __restrict__ h2b, const float* __restrict__ ST2,
                           float* __restrict__ out, u16* __restrict__ obb,
                           int N, int BPG) {
    int g = blockIdx.x / BPG;
    int idx = (blockIdx.x - g * BPG) * 256 + threadIdx.x;
    if (idx >= N * 16) return;
    int n = idx >> 4;
    int c4 = (idx & 15) << 2;
    const u16* hg = h2b + (long)g * N * 64;
    const float* st = ST2 + g * 256;
    ushort4 hv = *reinterpret_cast<const ushort4*>(hg + ((long)n << 6) + c4);
    const float4 sc = *reinterpret_cast<const float4*>(st + 128 + c4);
    const float4 sh = *reinterpret_cast<const float4*>(st + 192 + c4);
    float4 o;
    o.x = fmaxf(fmaf(bf2f(hv.x), sc.x, sh.x), 0.f);
    o.y = fmaxf(fmaf(bf2f(hv.y), sc.y, sh.y), 0.f);
    o.z = fmaxf(fmaf(bf2f(hv.z), sc.z, sh.z), 0.f);
    o.w = fmaxf(fmaf(bf2f(hv.w), sc.w, sh.w), 0.f);
    // g0 -> o_h0 (out + N*64), g1 -> o_h1 (out + 2N*64), g2(s) -> o_hs (out)
    float* yb = (g == 0) ? out + (long)N * 64 : (g == 1) ? out + (long)N * 128 : out;
    *reinterpret_cast<float4*>(yb + ((long)n << 6) + c4) = o;
    if (g < 2) {
        ushort4 ob = make_ushort4(f2bf(o.x), f2bf(o.y), f2bf(o.z), f2bf(o.w));
        *reinterpret_cast<ushort4*>(obb + (long)g * N * 64 + ((long)n << 6) + c4) = ob;
    }
}

static inline int cdiv(long a, int b) { return (int)((a + b - 1) / b); }

extern "C" void kernel_launch(void* const* d_in, const int* in_sizes, int n_in,
                              void* d_out, int out_size, void* d_ws, size_t ws_size,
                              hipStream_t stream) {
    const float* ft0 = (const float*)d_in[0];
    const float* ft1 = (const float*)d_in[1];
    const float* fs  = (const float*)d_in[2];
    const int* et0 = (const int*)d_in[3];
    const int* et1 = (const int*)d_in[4];
    const int* es  = (const int*)d_in[5];
    const float* aT0_W = (const float*)d_in[6];
    const float* aT0_b = (const float*)d_in[7];
    const float* aT0_g = (const float*)d_in[8];
    const float* aT0_be = (const float*)d_in[9];
    const float* aT1_W = (const float*)d_in[10];
    const float* aT1_b = (const float*)d_in[11];
    const float* aT1_g = (const float*)d_in[12];
    const float* aT1_be = (const float*)d_in[13];
    const float* aS_W = (const float*)d_in[14];
    const float* aS_b = (const float*)d_in[15];
    const float* aS_g = (const float*)d_in[16];
    const float* aS_be = (const float*)d_in[17];
    const float* ext_W = (const float*)d_in[18];
    const float* ext_b = (const float*)d_in[19];
    const float* ext_g = (const float*)d_in[20];
    const float* ext_be = (const float*)d_in[21];
    const float* rT0_W = (const float*)d_in[22];
    const float* rT0_b = (const float*)d_in[23];
    const float* rT1_W = (const float*)d_in[24];
    const float* rT1_b = (const float*)d_in[25];

    const int N = in_sizes[0] / 256;
    const int E = in_sizes[3] / 2;
    const int NB = cdiv(N, 256);
    const int nC = cdiv(E, CPE);
    const int MT = N / 16;

    float* out = (float*)d_out;
    float* o_f0 = out + (long)N * 192;      // [N,256]
    float* o_f1 = out + (long)N * 448;      // [N,128]

    // workspace
    char* p = (char*)d_ws;
    auto align16 = [&]() { p = (char*)(((uintptr_t)p + 15) & ~(uintptr_t)15); };
    u16* Yb  = (u16*)p;        p += (size_t)3 * N * 128 * 2;   // L1/L2 gemm outputs
    u16* Hb  = (u16*)p;        p += (size_t)3 * N * 128 * 2;   // L1 pre-BN agg (bf16)
    u16* h2b = (u16*)p;        p += (size_t)3 * N * 64 * 2;    // L2 pre-BN agg / L3 agg
    u16* obb = (u16*)p;        p += (size_t)2 * N * 64 * 2;    // bf16 o_h0/o_h1
    int* rp   = (int*)p;       p += (size_t)3 * (N + 1) * 4;
    int* sr   = (int*)p;       p += (size_t)3 * E * 4;
    unsigned* part = (unsigned*)p; p += (size_t)3 * E * 4;
    int* cnt  = (int*)p;       p += (size_t)3 * NB * nC * 4;
    int* ofs  = (int*)p;       p += (size_t)3 * NB * nC * 4;
    int* tot  = (int*)p;       p += (size_t)3 * NB * 4;
    int* baseE = (int*)p;      p += (size_t)3 * (NB + 1) * 4;
    align16();
    u16* WBF = (u16*)p;        p += (size_t)(256*128 + 128*128 + 256*128 + 128*64 + 64*256 + 64*128) * 2;
    align16();
    float* ST1 = (float*)p;    p += (size_t)3 * 512 * 4;
    float* ST2 = (float*)p;    p += (size_t)3 * 256 * 4;
    float* PARTS = (float*)p;  p += (size_t)3 * 256 * 256 * 4;

    u16* aT0b = WBF;
    u16* aT1b = aT0b + 256 * 128;
    u16* aSb  = aT1b + 128 * 128;
    u16* extb = aSb + 256 * 128;
    u16* rT0b = extb + 128 * 64;
    u16* rT1b = rT0b + 64 * 256;

    // ---- CSR build ----
    k_p1<<<3 * nC, 256, 0, stream>>>(et0, et1, es, cnt, E, nC, NB);
    k_p2a<<<3 * NB, 256, 0, stream>>>(cnt, tot, nC);
    k_p2b<<<3, 256, 0, stream>>>(tot, baseE, rp, E, N, NB);
    k_p2c<<<3 * NB, 256, 0, stream>>>(cnt, baseE, ofs, nC, NB);
    k_p3<<<3 * nC, 256, 0, stream>>>(et0, et1, es, ofs, part, E, nC, NB);
    k_p4<<<3 * NB, 256, 0, stream>>>(part, baseE, rp, sr, E, N, NB);

    // ---- weight converts (one launch) ----
    {
        int tot_w = 256*128 + 128*128 + 256*128 + 128*64 + 64*256 + 64*128;
        k_wcvt6<<<cdiv(tot_w, 256), 256, 0, stream>>>(
            aT0_W, aT1_W, aS_W, ext_W, rT0_W, rT1_W, WBF,
            256*128, 128*128, 256*128, 128*64, 64*256, 64*128);
    }

    const int B1 = cdiv((long)cdiv(N, 64) * 2, 4);   // L1: 64-row supertile x 2 col-halves, 4 waves/block
    const int B2 = cdiv(MT, 4);
    const int BPG = N / 8;           // agg blocks per graph (N % 8 == 0)
    const int BPA = cdiv((long)N * 16, 256);  // bnapply blocks per graph

    // ---- layer 1 ----
    k_gemmL1<<<3 * B1, 256, 0, stream>>>(ft0, ft1, fs, aT0b, aT1b, aSb,
                                         aT0_b, aT1_b, aS_b, Yb, N, B1);
    k_aggb3<128><<<3 * BPG, 256, 0, stream>>>(Yb, rp, sr, Hb, N, E, BPG);
    k_bnstats1<128><<<3 * 256, 256, 0, stream>>>(Hb, PARTS, N, 256 * 256);
    k_bnstats2<128><<<3, 128, 0, stream>>>(PARTS, aT0_g, aT1_g, aS_g,
                                           aT0_be, aT1_be, aS_be, ST1, 1.0f / N, 256 * 256);

    // ---- layer 2 ----
    k_gemmL2<<<3 * B2, 256, 0, stream>>>(Hb, ST1, extb, ext_b, Yb, MT, N, B2);
    k_aggb3<64><<<3 * BPG, 256, 0, stream>>>(Yb, rp, sr, h2b, N, E, BPG);
    k_bnstats1<64><<<3 * 256, 256, 0, stream>>>(h2b, PARTS, N, 256 * 128);
    k_bnstats2<64><<<3, 64, 0, stream>>>(PARTS, ext_g, ext_g, ext_g,
                                         ext_be, ext_be, ext_be, ST2, 1.0f / N, 256 * 128);
    k_bnapply3<<<3 * BPA, 256, 0, stream>>>(h2b, ST2, out, obb, N, BPA);

    // ---- layer 3 ----
    k_aggb3<64><<<2 * BPG, 256, 0, stream>>>(obb, rp, sr, h2b, N, E, BPG);
    k_gemmL3<<<MT + cdiv((long)MT * 2, 4), 256, 0, stream>>>(
        h2b, rT0b, rT1b, rT0_b, rT1_b, o_f0, o_f1, MT, N, MT);
}

// Round 16
// 459.224 us; speedup vs baseline: 1.2149x; 1.0553x over previous
//
#include <hip/hip_runtime.h>
#include <hip/hip_bf16.h>

#define CPE 8192   // edges per partition chunk

typedef short short8 __attribute__((ext_vector_type(8)));
typedef float f32x4 __attribute__((ext_vector_type(4)));
typedef float f32x2 __attribute__((ext_vector_type(2)));
using u16 = unsigned short;
using u8 = unsigned char;

#if __has_builtin(__builtin_amdgcn_cvt_pk_f32_fp8) && __has_builtin(__builtin_amdgcn_cvt_pk_fp8_f32)
#define FP8L1 1
#else
#define FP8L1 0
#endif

__device__ __forceinline__ float bf2f(u16 u) {
    return __uint_as_float(((unsigned)u) << 16);
}
__device__ __forceinline__ u16 f2bf(float f) {
    __hip_bfloat16 h = __float2bfloat16(f);   // RNE
    return *reinterpret_cast<u16*>(&h);
}

// ---------- batched weight convert: 6 fp32 arrays -> bf16 ----------
__global__ void k_wcvt6(const float* w0, const float* w1, const float* w2,
                        const float* w3, const float* w4, const float* w5,
                        u16* __restrict__ out,
                        int s0, int s1, int s2, int s3, int s4, int s5) {
    int i = blockIdx.x * blockDim.x + threadIdx.x;
    int b0 = s0, b1 = b0 + s1, b2 = b1 + s2, b3 = b2 + s3, b4 = b3 + s4, b5 = b4 + s5;
    if (i >= b5) return;
    const float* w;
    int o;
    if (i < b0) { w = w0; o = i; }
    else if (i < b1) { w = w1; o = i - b0; }
    else if (i < b2) { w = w2; o = i - b1; }
    else if (i < b3) { w = w3; o = i - b2; }
    else if (i < b4) { w = w4; o = i - b3; }
    else { w = w5; o = i - b4; }
    out[i] = f2bf(w[o]);
}

// ================= CSR build via coarse-bucket counting sort =================
// record u32 = ((dst & 255) << 16) | src   (requires N <= 65536)

__global__ void k_p1(const int* __restrict__ e0, const int* __restrict__ e1,
                     const int* __restrict__ e2, int* __restrict__ cnt,
                     int E, int nC, int NB) {
    __shared__ int h[256];
    int g = blockIdx.x / nC, c = blockIdx.x - g * nC;
    const int* dst = (g == 0 ? e0 : g == 1 ? e1 : e2) + E;
    for (int b = threadIdx.x; b < NB; b += 256) h[b] = 0;
    __syncthreads();
    int lo = c * CPE, hi = min(E, lo + CPE);
    for (int e = lo + threadIdx.x; e < hi; e += 256)
        atomicAdd(&h[dst[e] >> 8], 1);
    __syncthreads();
    for (int b = threadIdx.x; b < NB; b += 256)
        cnt[((long)g * NB + b) * nC + c] = h[b];
}

__global__ void k_p2a(const int* __restrict__ cnt, int* __restrict__ tot, int nC) {
    __shared__ int s[256];
    long gb = blockIdx.x;
    const int* row = cnt + gb * nC;
    int v = 0;
    for (int c = threadIdx.x; c < nC; c += 256) v += row[c];
    s[threadIdx.x] = v;
    __syncthreads();
    for (int o = 128; o > 0; o >>= 1) {
        if (threadIdx.x < o) s[threadIdx.x] += s[threadIdx.x + o];
        __syncthreads();
    }
    if (threadIdx.x == 0) tot[gb] = s[0];
}

__global__ void k_p2b(const int* __restrict__ tot, int* __restrict__ baseE,
                      int* __restrict__ rowptr, int E, int N, int NB) {
    __shared__ int s[256];
    int g = blockIdx.x, t = threadIdx.x;
    int v = (t < NB) ? tot[g * NB + t] : 0;
    s[t] = v;
    __syncthreads();
    for (int o = 1; o < 256; o <<= 1) {
        int a = (t >= o) ? s[t - o] : 0;
        __syncthreads();
        s[t] += a;
        __syncthreads();
    }
    if (t < NB) baseE[g * (NB + 1) + t] = s[t] - v;
    if (t == 0) {
        baseE[g * (NB + 1) + NB] = E;
        rowptr[(long)g * (N + 1) + N] = E;
    }
}

__global__ void k_p2c(const int* __restrict__ cnt, const int* __restrict__ baseE,
                      int* __restrict__ ofs, int nC, int NB) {
    __shared__ int s[256];
    long gb = blockIdx.x;
    int g = (int)(gb / NB), b = (int)(gb - (long)g * NB);
    int t = threadIdx.x;
    int v = (t < nC) ? cnt[gb * nC + t] : 0;
    s[t] = v;
    __syncthreads();
    for (int o = 1; o < 256; o <<= 1) {
        int a = (t >= o) ? s[t - o] : 0;
        __syncthreads();
        s[t] += a;
        __syncthreads();
    }
    if (t < nC) ofs[gb * nC + t] = baseE[g * (NB + 1) + b] + s[t] - v;
}

__global__ void k_p3(const int* __restrict__ e0, const int* __restrict__ e1,
                     const int* __restrict__ e2, const int* __restrict__ ofs,
                     unsigned* __restrict__ part, int E, int nC, int NB) {
    __shared__ int lbase[256];
    __shared__ int lcur[256];
    int g = blockIdx.x / nC, c = blockIdx.x - g * nC;
    const int* eg = (g == 0 ? e0 : g == 1 ? e1 : e2);
    const int* src = eg;
    const int* dst = eg + E;
    for (int b = threadIdx.x; b < NB; b += 256) {
        lbase[b] = ofs[((long)g * NB + b) * nC + c];
        lcur[b] = 0;
    }
    __syncthreads();
    int lo = c * CPE, hi = min(E, lo + CPE);
    unsigned* pg = part + (long)g * E;
    for (int e = lo + threadIdx.x; e < hi; e += 256) {
        int d = dst[e];
        int b = d >> 8;
        int pos = lbase[b] + atomicAdd(&lcur[b], 1);
        pg[pos] = ((unsigned)(d & 255) << 16) | (unsigned)src[e];
    }
}

__global__ void k_p4(const unsigned* __restrict__ part, const int* __restrict__ baseE,
                     int* __restrict__ rowptr, int* __restrict__ srcs,
                     int E, int N, int NB) {
    __shared__ int h[256];
    __shared__ int s[256];
    __shared__ int cur[256];
    int g = blockIdx.x / NB, b = blockIdx.x - g * NB;
    int n0 = b << 8;
    int nn = min(256, N - n0);
    int lo = baseE[g * (NB + 1) + b], hi = baseE[g * (NB + 1) + b + 1];
    int t = threadIdx.x;
    h[t] = 0;
    __syncthreads();
    const unsigned* pg = part + (long)g * E;
    for (int i = lo + t; i < hi; i += 256)
        atomicAdd(&h[pg[i] >> 16], 1);
    __syncthreads();
    int v = h[t];
    s[t] = v;
    __syncthreads();
    for (int o = 1; o < 256; o <<= 1) {
        int a = (t >= o) ? s[t - o] : 0;
        __syncthreads();
        s[t] += a;
        __syncthreads();
    }
    int excl = lo + s[t] - v;
    if (t < nn) rowptr[(long)g * (N + 1) + n0 + t] = excl;
    cur[t] = excl;
    __syncthreads();
    int* sg = srcs + (long)g * E;
    for (int i = lo + t; i < hi; i += 256) {
        unsigned r = pg[i];
        int pos = atomicAdd(&cur[r >> 16], 1);
        sg[pos] = (int)(r & 0xFFFFu);
    }
}

// ---------- generic MFMA GEMM core (used by L2/L3; 16 rows/wave) ----------
template <bool ABF, bool BN_IN, bool RELU_OUT, bool BF16_OUT>
__device__ __forceinline__ void gemm_body(const void* X, const float* stats,
                                          const u16* __restrict__ Wb,
                                          const float* __restrict__ bias,
                                          void* Yv, int MT, int Cin, int SH,
                                          int wl, int l) {
    int mt = wl >> SH;
    if (mt >= MT) return;
    int CG = 1 << SH;
    int COUT = CG * 64;
    int cg = wl & (CG - 1);
    int lm = l & 15, lh = l >> 4;
    int kb = lh * 8;

    const float* xrf = nullptr;
    const u16* xrb = nullptr;
    if (ABF) xrb = (const u16*)X + (long)(mt * 16 + lm) * Cin + kb;
    else     xrf = (const float*)X + (long)(mt * 16 + lm) * Cin + kb;
    const u16* wp[4];
#pragma unroll
    for (int t = 0; t < 4; ++t)
        wp[t] = Wb + (long)(cg * 64 + t * 16 + lm) * Cin + kb;
    const float* scp = nullptr;
    const float* shp = nullptr;
    if (BN_IN) {
        scp = stats + 2 * Cin + kb;
        shp = stats + 3 * Cin + kb;
    }

    f32x4 acc[4];
#pragma unroll
    for (int t = 0; t < 4; ++t) acc[t] = (f32x4){0.f, 0.f, 0.f, 0.f};

    for (int k0 = 0; k0 < Cin; k0 += 32) {
        short8 a;
        if (ABF) {
            short8 raw = *reinterpret_cast<const short8*>(xrb);
            if (BN_IN) {
#pragma unroll
                for (int j = 0; j < 8; ++j) {
                    float x = bf2f((u16)raw[j]);
                    x = fmaxf(fmaf(x, scp[j], shp[j]), 0.f);
                    a[j] = (short)f2bf(x);
                }
                scp += 32; shp += 32;
            } else {
                a = raw;
            }
            xrb += 32;
        } else {
            float4 x0 = *reinterpret_cast<const float4*>(xrf);
            float4 x1 = *reinterpret_cast<const float4*>(xrf + 4);
            a[0] = (short)f2bf(x0.x); a[1] = (short)f2bf(x0.y);
            a[2] = (short)f2bf(x0.z); a[3] = (short)f2bf(x0.w);
            a[4] = (short)f2bf(x1.x); a[5] = (short)f2bf(x1.y);
            a[6] = (short)f2bf(x1.z); a[7] = (short)f2bf(x1.w);
            xrf += 32;
        }
#pragma unroll
        for (int t = 0; t < 4; ++t) {
            short8 b = *reinterpret_cast<const short8*>(wp[t]);
            acc[t] = __builtin_amdgcn_mfma_f32_16x16x32_bf16(a, b, acc[t], 0, 0, 0);
            wp[t] += 32;
        }
    }

    int nb = mt * 16 + lh * 4;
#pragma unroll
    for (int t = 0; t < 4; ++t) {
        int col = cg * 64 + t * 16 + lm;
        float bi = bias[col];
#pragma unroll
        for (int r = 0; r < 4; ++r) {
            float v = acc[t][r] + bi;
            if (RELU_OUT) v = fmaxf(v, 0.f);
            if (BF16_OUT)
                ((u16*)Yv)[(long)(nb + r) * COUT + col] = f2bf(v);
            else
                ((float*)Yv)[(long)(nb + r) * COUT + col] = v;
        }
    }
}

// ---------- L1 GEMM m4: 64 rows x 64 cols per wave; B reused across 4 M-frags ----------
// Output: fp8 e4m3 (128 B/row) when FP8L1, else bf16. OOB: clamped loads, guarded stores.
__device__ __forceinline__ void gemmL1m4(const float* __restrict__ X,
                                         const u16* __restrict__ Wb,
                                         const float* __restrict__ bias,
                                         u16* __restrict__ Yb,
                                         int N, int Cin, int wl, int l) {
    int mt = wl >> 1;          // 64-row supertile
    int cg = wl & 1;           // 64-col half
    int m0 = mt * 64;
    if (m0 >= N) return;
    int lm = l & 15, lh = l >> 4;
    int kb = lh * 8;

    const u16* wp[4];
#pragma unroll
    for (int t = 0; t < 4; ++t)
        wp[t] = Wb + (long)(cg * 64 + t * 16 + lm) * Cin + kb;

    const float* xr[4];
#pragma unroll
    for (int mi = 0; mi < 4; ++mi) {
        int row = m0 + mi * 16 + lm;
        if (row >= N) row = N - 1;   // clamp: garbage lands only in unstored D rows
        xr[mi] = X + (long)row * Cin + kb;
    }

    f32x4 acc[4][4];
#pragma unroll
    for (int mi = 0; mi < 4; ++mi)
#pragma unroll
        for (int t = 0; t < 4; ++t) acc[mi][t] = (f32x4){0.f, 0.f, 0.f, 0.f};

    for (int k0 = 0; k0 < Cin; k0 += 32) {
        short8 b[4];
#pragma unroll
        for (int t = 0; t < 4; ++t) {
            b[t] = *reinterpret_cast<const short8*>(wp[t]);
            wp[t] += 32;
        }
        short8 a[4];
#pragma unroll
        for (int mi = 0; mi < 4; ++mi) {
            float4 x0 = *reinterpret_cast<const float4*>(xr[mi]);
            float4 x1 = *reinterpret_cast<const float4*>(xr[mi] + 4);
            xr[mi] += 32;
            a[mi][0] = (short)f2bf(x0.x); a[mi][1] = (short)f2bf(x0.y);
            a[mi][2] = (short)f2bf(x0.z); a[mi][3] = (short)f2bf(x0.w);
            a[mi][4] = (short)f2bf(x1.x); a[mi][5] = (short)f2bf(x1.y);
            a[mi][6] = (short)f2bf(x1.z); a[mi][7] = (short)f2bf(x1.w);
        }
#pragma unroll
        for (int mi = 0; mi < 4; ++mi)
#pragma unroll
            for (int t = 0; t < 4; ++t)
                acc[mi][t] = __builtin_amdgcn_mfma_f32_16x16x32_bf16(a[mi], b[t], acc[mi][t], 0, 0, 0);
    }

#pragma unroll
    for (int mi = 0; mi < 4; ++mi) {
        int nb = m0 + mi * 16 + lh * 4;
#pragma unroll
        for (int t = 0; t < 4; ++t) {
            int col = cg * 64 + t * 16 + lm;
            float bi = bias[col];
#if FP8L1
            float v0 = acc[mi][t][0] + bi, v1 = acc[mi][t][1] + bi;
            float v2 = acc[mi][t][2] + bi, v3 = acc[mi][t][3] + bi;
            int p01 = __builtin_amdgcn_cvt_pk_fp8_f32(v0, v1, 0, false);
            int p23 = __builtin_amdgcn_cvt_pk_fp8_f32(v2, v3, 0, false);
            u8* Y8 = reinterpret_cast<u8*>(Yb);
            if (nb + 0 < N) Y8[(long)(nb + 0) * 128 + col] = (u8)(p01 & 0xff);
            if (nb + 1 < N) Y8[(long)(nb + 1) * 128 + col] = (u8)((p01 >> 8) & 0xff);
            if (nb + 2 < N) Y8[(long)(nb + 2) * 128 + col] = (u8)(p23 & 0xff);
            if (nb + 3 < N) Y8[(long)(nb + 3) * 128 + col] = (u8)((p23 >> 8) & 0xff);
#else
#pragma unroll
            for (int r = 0; r < 4; ++r) {
                int row = nb + r;
                if (row < N)
                    Yb[(long)row * 128 + col] = f2bf(acc[mi][t][r] + bi);
            }
#endif
        }
    }
}

__global__ __launch_bounds__(256) void k_gemmL1(
        const float* x0, const float* x1, const float* x2,
        const u16* w0, const u16* w1, const u16* w2,
        const float* b0, const float* b1, const float* b2,
        u16* Yb, int N, int B1) {
    int g = blockIdx.x / B1;
    int wl = (blockIdx.x - g * B1) * 4 + (threadIdx.x >> 6);
    int l = threadIdx.x & 63;
    const float* x = g == 0 ? x0 : (g == 1 ? x1 : x2);
    const u16* w = g == 0 ? w0 : (g == 1 ? w1 : w2);
    const float* b = g == 0 ? b0 : (g == 1 ? b1 : b2);
    int cin = (g == 1) ? 128 : 256;
    gemmL1m4(x, w, b, Yb + (long)g * N * 128, N, cin, wl, l);
}

// L2: 3 graphs, A bf16 + BN_IN, shared weights, CG=1 (Cout 64), bf16 out
// output stride between graphs is N*64 (COUT=64) to match k_aggb3<64>.
__global__ __launch_bounds__(256) void k_gemmL2(
        const u16* Hb, const float* ST, const u16* wext, const float* bext,
        u16* Yb, int MT, int N, int B2) {
    int g = blockIdx.x / B2;
    int wl = (blockIdx.x - g * B2) * 4 + (threadIdx.x >> 6);
    gemm_body<true, true, false, true>(Hb + (long)g * N * 128, ST + g * 512, wext,
                                       bext, Yb + (long)g * N * 64, MT, 128, 0,
                                       wl, threadIdx.x & 63);
}

// L3: 2 graphs, A bf16, fp32 relu out; g0: CG=4 Cout256 -> f0, g1: CG=2 Cout128 -> f1
__global__ __launch_bounds__(256) void k_gemmL3(
        const u16* h3, const u16* wr0, const u16* wr1,
        const float* br0, const float* br1,
        float* f0, float* f1, int MT, int N, int B0) {
    int b = blockIdx.x;
    int g = (b < B0) ? 0 : 1;
    int wl = (g == 0 ? b : b - B0) * 4 + (threadIdx.x >> 6);
    if (g == 0)
        gemm_body<true, false, true, false>(h3, nullptr, wr0, br0, f0, MT, 64, 2,
                                            wl, threadIdx.x & 63);
    else
        gemm_body<true, false, true, false>(h3 + (long)N * 64, nullptr, wr1, br1,
                                            f1, MT, 64, 1, wl, threadIdx.x & 63);
}

// ---------- batched aggregation: out[n] = in[n] + sum_{e} in[src[e]] ----------
// CH=128: input fp8 (FP8L1) or bf16; output bf16. CH=64: bf16 in/out. fp32 accum.
template <int CH>
__global__ void k_aggb3(const u16* __restrict__ in, const int* __restrict__ rp,
                        const int* __restrict__ sr, u16* __restrict__ outb,
                        int N, int E, int BPG) {
    int g = blockIdx.x / BPG;
    int bb = blockIdx.x - g * BPG;
    int l = threadIdx.x & 63;
    int ll = l & 31;
    int n = (bb << 3) + ((threadIdx.x >> 6) << 1) + (l >> 5);
    if (n >= N) return;
    const int* rowptr = rp + (long)g * (N + 1);
    const int* srcs = sr + (long)g * E;
    int p = rowptr[n], p1 = rowptr[n + 1];
    if constexpr (CH == 128) {
#if FP8L1
        const unsigned* Yp = reinterpret_cast<const unsigned*>(in + (long)g * N * 128) + ll;
        unsigned a = Yp[(long)n << 5];
        f32x2 alo = __builtin_amdgcn_cvt_pk_f32_fp8(a, false);
        f32x2 ahi = __builtin_amdgcn_cvt_pk_f32_fp8(a, true);
        float s0 = alo[0], s1 = alo[1], s2 = ahi[0], s3 = ahi[1];
        while (p + 8 <= p1) {
            unsigned r[8];
#pragma unroll
            for (int j = 0; j < 8; ++j) r[j] = Yp[(long)srcs[p + j] << 5];
#pragma unroll
            for (int j = 0; j < 8; ++j) {
                f32x2 lo = __builtin_amdgcn_cvt_pk_f32_fp8(r[j], false);
                f32x2 hi = __builtin_amdgcn_cvt_pk_f32_fp8(r[j], true);
                s0 += lo[0]; s1 += lo[1]; s2 += hi[0]; s3 += hi[1];
            }
            p += 8;
        }
        while (p < p1) {
            unsigned r = Yp[(long)srcs[p] << 5];
            f32x2 lo = __builtin_amdgcn_cvt_pk_f32_fp8(r, false);
            f32x2 hi = __builtin_amdgcn_cvt_pk_f32_fp8(r, true);
            s0 += lo[0]; s1 += lo[1]; s2 += hi[0]; s3 += hi[1];
            ++p;
        }
#else
        const ushort4* Yp = reinterpret_cast<const ushort4*>(in + (long)g * N * 128) + ll;
        ushort4 a = Yp[(long)n << 5];
        float s0 = bf2f(a.x), s1 = bf2f(a.y), s2 = bf2f(a.z), s3 = bf2f(a.w);
        while (p + 8 <= p1) {
            ushort4 r[8];
#pragma unroll
            for (int j = 0; j < 8; ++j) r[j] = Yp[(long)srcs[p + j] << 5];
#pragma unroll
            for (int j = 0; j < 8; ++j) {
                s0 += bf2f(r[j].x); s1 += bf2f(r[j].y);
                s2 += bf2f(r[j].z); s3 += bf2f(r[j].w);
            }
            p += 8;
        }
        while (p < p1) {
            ushort4 r = Yp[(long)srcs[p] << 5];
            s0 += bf2f(r.x); s1 += bf2f(r.y); s2 += bf2f(r.z); s3 += bf2f(r.w);
            ++p;
        }
#endif
        ushort4 o = make_ushort4(f2bf(s0), f2bf(s1), f2bf(s2), f2bf(s3));
        (reinterpret_cast<ushort4*>(outb + (long)g * N * 128) + ll)[(long)n << 5] = o;
    } else {
        const unsigned* Yp = reinterpret_cast<const unsigned*>(in + (long)g * N * 64) + ll;
        unsigned a = Yp[(long)n << 5];
        float s0 = bf2f((u16)a), s1 = bf2f((u16)(a >> 16));
        while (p + 8 <= p1) {
            unsigned r[8];
#pragma unroll
            for (int j = 0; j < 8; ++j) r[j] = Yp[(long)srcs[p + j] << 5];
#pragma unroll
            for (int j = 0; j < 8; ++j) {
                s0 += bf2f((u16)r[j]);
                s1 += bf2f((u16)(r[j] >> 16));
            }
            p += 8;
        }
        while (p < p1) {
            unsigned r = Yp[(long)srcs[p] << 5];
            s0 += bf2f((u16)r);
            s1 += bf2f((u16)(r >> 16));
            ++p;
        }
        unsigned o = (unsigned)f2bf(s0) | ((unsigned)f2bf(s1) << 16);
        (reinterpret_cast<unsigned*>(outb + (long)g * N * 64) + ll)[(long)n << 5] = o;
    }
}

// ---------- BN stats (bf16 input), two-stage deterministic, batched ----------
template <int C>
__global__ void k_bnstats1(const u16* __restrict__ h, float* __restrict__ parts,
                           int N, int PSTRIDE) {
    constexpr int RPB = 256 / C;
    constexpr int LGC = (C == 128) ? 7 : 6;
    __shared__ float ts[256], ts2[256];
    int g = blockIdx.x >> 8;
    int blk = blockIdx.x & 255;
    const u16* hg = h + (long)g * N * C;
    float* pg = parts + (long)g * PSTRIDE;
    int tid = threadIdx.x;
    int c = tid & (C - 1);
    float s = 0.f, s2 = 0.f;
    for (int n = blk * RPB + (tid >> LGC); n < N; n += 256 * RPB) {
        float v = bf2f(hg[((long)n << LGC) + c]);
        s += v;
        s2 = fmaf(v, v, s2);
    }
    ts[tid] = s;
    ts2[tid] = s2;
    __syncthreads();
    if (tid < C) {
#pragma unroll
        for (int i = 1; i < RPB; ++i) {
            s += ts[tid + i * C];
            s2 += ts2[tid + i * C];
        }
        pg[blk * 2 * C + tid] = s;
        pg[blk * 2 * C + C + tid] = s2;
    }
}

template <int C>
__global__ void k_bnstats2(const float* __restrict__ parts,
                           const float* g0, const float* g1, const float* g2,
                           const float* b0, const float* b1, const float* b2,
                           float* __restrict__ ST, float invN, int PSTRIDE) {
    int g = blockIdx.x;
    const float* gam = g == 0 ? g0 : (g == 1 ? g1 : g2);
    const float* bet = g == 0 ? b0 : (g == 1 ? b1 : b2);
    const float* pg = parts + (long)g * PSTRIDE;
    float* st = ST + g * 4 * C;
    int c = threadIdx.x;
    float s = 0.f, s2 = 0.f;
    for (int b = 0; b < 256; ++b) {
        s += pg[b * 2 * C + c];
        s2 += pg[b * 2 * C + C + c];
    }
    float m = s * invN;
    float v = s2 * invN - m * m;
    float sc = gam[c] * rsqrtf(v + 1e-5f);
    st[2 * C + c] = sc;
    st[3 * C + c] = bet[c] - m * sc;
}

// ---------- batched BN apply (bf16 in, fp32 out + bf16 copy for g<2) ----------
__global__ void k_bnapply3(const u16* __restrict__ h2b, const float* __restrict__ ST2,
                           float* __restrict__ out, u16* __restrict__ obb,
                           int N, int BPG) {
    int g = blockIdx.x / BPG;
    int idx = (blockIdx.x - g * BPG) * 256 + threadIdx.x;
    if (idx >= N * 16) return;
    int n = idx >> 4;
    int c4 = (idx & 15) << 2;
    const u16* hg = h2b + (long)g * N * 64;
    const float* st = ST2 + g * 256;
    ushort4 hv = *reinterpret_cast<const ushort4*>(hg + ((long)n << 6) + c4);
    const float4 sc = *reinterpret_cast<const float4*>(st + 128 + c4);
    const float4 sh = *reinterpret_cast<const float4*>(st + 192 + c4);
    float4 o;
    o.x = fmaxf(fmaf(bf2f(hv.x), sc.x, sh.x), 0.f);
    o.y = fmaxf(fmaf(bf2f(hv.y), sc.y, sh.y), 0.f);
    o.z = fmaxf(fmaf(bf2f(hv.z), sc.z, sh.z), 0.f);
    o.w = fmaxf(fmaf(bf2f(hv.w), sc.w, sh.w), 0.f);
    // g0 -> o_h0 (out + N*64), g1 -> o_h1 (out + 2N*64), g2(s) -> o_hs (out)
    float* yb = (g == 0) ? out + (long)N * 64 : (g == 1) ? out + (long)N * 128 : out;
    *reinterpret_cast<float4*>(yb + ((long)n << 6) + c4) = o;
    if (g < 2) {
        ushort4 ob = make_ushort4(f2bf(o.x), f2bf(o.y), f2bf(o.z), f2bf(o.w));
        *reinterpret_cast<ushort4*>(obb + (long)g * N * 64 + ((long)n << 6) + c4) = ob;
    }
}

static inline int cdiv(long a, int b) { return (int)((a + b - 1) / b); }

extern "C" void kernel_launch(void* const* d_in, const int* in_sizes, int n_in,
                              void* d_out, int out_size, void* d_ws, size_t ws_size,
                              hipStream_t stream) {
    const float* ft0 = (const float*)d_in[0];
    const float* ft1 = (const float*)d_in[1];
    const float* fs  = (const float*)d_in[2];
    const int* et0 = (const int*)d_in[3];
    const int* et1 = (const int*)d_in[4];
    const int* es  = (const int*)d_in[5];
    const float* aT0_W = (const float*)d_in[6];
    const float* aT0_b = (const float*)d_in[7];
    const float* aT0_g = (const float*)d_in[8];
    const float* aT0_be = (const float*)d_in[9];
    const float* aT1_W = (const float*)d_in[10];
    const float* aT1_b = (const float*)d_in[11];
    const float* aT1_g = (const float*)d_in[12];
    const float* aT1_be = (const float*)d_in[13];
    const float* aS_W = (const float*)d_in[14];
    const float* aS_b = (const float*)d_in[15];
    const float* aS_g = (const float*)d_in[16];
    const float* aS_be = (const float*)d_in[17];
    const float* ext_W = (const float*)d_in[18];
    const float* ext_b = (const float*)d_in[19];
    const float* ext_g = (const float*)d_in[20];
    const float* ext_be = (const float*)d_in[21];
    const float* rT0_W = (const float*)d_in[22];
    const float* rT0_b = (const float*)d_in[23];
    const float* rT1_W = (const float*)d_in[24];
    const float* rT1_b = (const float*)d_in[25];

    const int N = in_sizes[0] / 256;
    const int E = in_sizes[3] / 2;
    const int NB = cdiv(N, 256);
    const int nC = cdiv(E, CPE);
    const int MT = N / 16;

    float* out = (float*)d_out;
    float* o_f0 = out + (long)N * 192;      // [N,256]
    float* o_f1 = out + (long)N * 448;      // [N,128]

    // workspace
    char* p = (char*)d_ws;
    auto align16 = [&]() { p = (char*)(((uintptr_t)p + 15) & ~(uintptr_t)15); };
    u16* Yb  = (u16*)p;        p += (size_t)3 * N * 128 * 2;   // L1 (fp8/bf16) / L2 gemm outputs
    u16* Hb  = (u16*)p;        p += (size_t)3 * N * 128 * 2;   // L1 pre-BN agg (bf16)
    u16* h2b = (u16*)p;        p += (size_t)3 * N * 64 * 2;    // L2 pre-BN agg / L3 agg
    u16* obb = (u16*)p;        p += (size_t)2 * N * 64 * 2;    // bf16 o_h0/o_h1
    int* rp   = (int*)p;       p += (size_t)3 * (N + 1) * 4;
    int* sr   = (int*)p;       p += (size_t)3 * E * 4;
    unsigned* part = (unsigned*)p; p += (size_t)3 * E * 4;
    int* cnt  = (int*)p;       p += (size_t)3 * NB * nC * 4;
    int* ofs  = (int*)p;       p += (size_t)3 * NB * nC * 4;
    int* tot  = (int*)p;       p += (size_t)3 * NB * 4;
    int* baseE = (int*)p;      p += (size_t)3 * (NB + 1) * 4;
    align16();
    u16* WBF = (u16*)p;        p += (size_t)(256*128 + 128*128 + 256*128 + 128*64 + 64*256 + 64*128) * 2;
    align16();
    float* ST1 = (float*)p;    p += (size_t)3 * 512 * 4;
    float* ST2 = (float*)p;    p += (size_t)3 * 256 * 4;
    float* PARTS = (float*)p;  p += (size_t)3 * 256 * 256 * 4;

    u16* aT0b = WBF;
    u16* aT1b = aT0b + 256 * 128;
    u16* aSb  = aT1b + 128 * 128;
    u16* extb = aSb + 256 * 128;
    u16* rT0b = extb + 128 * 64;
    u16* rT1b = rT0b + 64 * 256;

    // ---- CSR build ----
    k_p1<<<3 * nC, 256, 0, stream>>>(et0, et1, es, cnt, E, nC, NB);
    k_p2a<<<3 * NB, 256, 0, stream>>>(cnt, tot, nC);
    k_p2b<<<3, 256, 0, stream>>>(tot, baseE, rp, E, N, NB);
    k_p2c<<<3 * NB, 256, 0, stream>>>(cnt, baseE, ofs, nC, NB);
    k_p3<<<3 * nC, 256, 0, stream>>>(et0, et1, es, ofs, part, E, nC, NB);
    k_p4<<<3 * NB, 256, 0, stream>>>(part, baseE, rp, sr, E, N, NB);

    // ---- weight converts (one launch) ----
    {
        int tot_w = 256*128 + 128*128 + 256*128 + 128*64 + 64*256 + 64*128;
        k_wcvt6<<<cdiv(tot_w, 256), 256, 0, stream>>>(
            aT0_W, aT1_W, aS_W, ext_W, rT0_W, rT1_W, WBF,
            256*128, 128*128, 256*128, 128*64, 64*256, 64*128);
    }

    const int B1 = cdiv((long)cdiv(N, 64) * 2, 4);   // L1: 64-row supertile x 2 col-halves
    const int B2 = cdiv(MT, 4);
    const int BPG = N / 8;           // agg blocks per graph (N % 8 == 0)
    const int BPA = cdiv((long)N * 16, 256);  // bnapply blocks per graph

    // ---- layer 1 ----
    k_gemmL1<<<3 * B1, 256, 0, stream>>>(ft0, ft1, fs, aT0b, aT1b, aSb,
                                         aT0_b, aT1_b, aS_b, Yb, N, B1);
    k_aggb3<128><<<3 * BPG, 256, 0, stream>>>(Yb, rp, sr, Hb, N, E, BPG);
    k_bnstats1<128><<<3 * 256, 256, 0, stream>>>(Hb, PARTS, N, 256 * 256);
    k_bnstats2<128><<<3, 128, 0, stream>>>(PARTS, aT0_g, aT1_g, aS_g,
                                           aT0_be, aT1_be, aS_be, ST1, 1.0f / N, 256 * 256);

    // ---- layer 2 ----
    k_gemmL2<<<3 * B2, 256, 0, stream>>>(Hb, ST1, extb, ext_b, Yb, MT, N, B2);
    k_aggb3<64><<<3 * BPG, 256, 0, stream>>>(Yb, rp, sr, h2b, N, E, BPG);
    k_bnstats1<64><<<3 * 256, 256, 0, stream>>>(h2b, PARTS, N, 256 * 128);
    k_bnstats2<64><<<3, 64, 0, stream>>>(PARTS, ext_g, ext_g, ext_g,
                                         ext_be, ext_be, ext_be, ST2, 1.0f / N, 256 * 128);
    k_bnapply3<<<3 * BPA, 256, 0, stream>>>(h2b, ST2, out, obb, N, BPA);

    // ---- layer 3 ----
    k_aggb3<64><<<2 * BPG, 256, 0, stream>>>(obb, rp, sr, h2b, N, E, BPG);
    k_gemmL3<<<MT + cdiv((long)MT * 2, 4), 256, 0, stream>>>(
        h2b, rT0b, rT1b, rT0_b, rT1_b, o_f0, o_f1, MT, N, MT);
}

// Round 19
// 457.612 us; speedup vs baseline: 1.2192x; 1.0035x over previous
//
#include <hip/hip_runtime.h>
#include <hip/hip_bf16.h>

#define CPE 8192   // edges per partition chunk

typedef short short8 __attribute__((ext_vector_type(8)));
typedef float f32x4 __attribute__((ext_vector_type(4)));
typedef float f32x2 __attribute__((ext_vector_type(2)));
using u16 = unsigned short;
using u8 = unsigned char;

#if __has_builtin(__builtin_amdgcn_cvt_pk_f32_fp8) && __has_builtin(__builtin_amdgcn_cvt_pk_fp8_f32)
#define FP8L1 1
#else
#define FP8L1 0
#endif

__device__ __forceinline__ float bf2f(u16 u) {
    return __uint_as_float(((unsigned)u) << 16);
}
__device__ __forceinline__ u16 f2bf(float f) {
    __hip_bfloat16 h = __float2bfloat16(f);   // RNE
    return *reinterpret_cast<u16*>(&h);
}

// ---------- batched weight convert: 6 fp32 arrays -> bf16 ----------
__global__ void k_wcvt6(const float* w0, const float* w1, const float* w2,
                        const float* w3, const float* w4, const float* w5,
                        u16* __restrict__ out,
                        int s0, int s1, int s2, int s3, int s4, int s5) {
    int i = blockIdx.x * blockDim.x + threadIdx.x;
    int b0 = s0, b1 = b0 + s1, b2 = b1 + s2, b3 = b2 + s3, b4 = b3 + s4, b5 = b4 + s5;
    if (i >= b5) return;
    const float* w;
    int o;
    if (i < b0) { w = w0; o = i; }
    else if (i < b1) { w = w1; o = i - b0; }
    else if (i < b2) { w = w2; o = i - b1; }
    else if (i < b3) { w = w3; o = i - b2; }
    else if (i < b4) { w = w4; o = i - b3; }
    else { w = w5; o = i - b4; }
    out[i] = f2bf(w[o]);
}

// ================= CSR build via coarse-bucket counting sort =================
// record u32 = ((dst & 255) << 16) | src   (requires N <= 65536)

__global__ void k_p1(const int* __restrict__ e0, const int* __restrict__ e1,
                     const int* __restrict__ e2, int* __restrict__ cnt,
                     int E, int nC, int NB) {
    __shared__ int h[256];
    int g = blockIdx.x / nC, c = blockIdx.x - g * nC;
    const int* dst = (g == 0 ? e0 : g == 1 ? e1 : e2) + E;
    for (int b = threadIdx.x; b < NB; b += 256) h[b] = 0;
    __syncthreads();
    int lo = c * CPE, hi = min(E, lo + CPE);
    for (int e = lo + threadIdx.x; e < hi; e += 256)
        atomicAdd(&h[dst[e] >> 8], 1);
    __syncthreads();
    for (int b = threadIdx.x; b < NB; b += 256)
        cnt[((long)g * NB + b) * nC + c] = h[b];
}

__global__ void k_p2a(const int* __restrict__ cnt, int* __restrict__ tot, int nC) {
    __shared__ int s[256];
    long gb = blockIdx.x;
    const int* row = cnt + gb * nC;
    int v = 0;
    for (int c = threadIdx.x; c < nC; c += 256) v += row[c];
    s[threadIdx.x] = v;
    __syncthreads();
    for (int o = 128; o > 0; o >>= 1) {
        if (threadIdx.x < o) s[threadIdx.x] += s[threadIdx.x + o];
        __syncthreads();
    }
    if (threadIdx.x == 0) tot[gb] = s[0];
}

__global__ void k_p2b(const int* __restrict__ tot, int* __restrict__ baseE,
                      int* __restrict__ rowptr, int E, int N, int NB) {
    __shared__ int s[256];
    int g = blockIdx.x, t = threadIdx.x;
    int v = (t < NB) ? tot[g * NB + t] : 0;
    s[t] = v;
    __syncthreads();
    for (int o = 1; o < 256; o <<= 1) {
        int a = (t >= o) ? s[t - o] : 0;
        __syncthreads();
        s[t] += a;
        __syncthreads();
    }
    if (t < NB) baseE[g * (NB + 1) + t] = s[t] - v;
    if (t == 0) {
        baseE[g * (NB + 1) + NB] = E;
        rowptr[(long)g * (N + 1) + N] = E;
    }
}

__global__ void k_p2c(const int* __restrict__ cnt, const int* __restrict__ baseE,
                      int* __restrict__ ofs, int nC, int NB) {
    __shared__ int s[256];
    long gb = blockIdx.x;
    int g = (int)(gb / NB), b = (int)(gb - (long)g * NB);
    int t = threadIdx.x;
    int v = (t < nC) ? cnt[gb * nC + t] : 0;
    s[t] = v;
    __syncthreads();
    for (int o = 1; o < 256; o <<= 1) {
        int a = (t >= o) ? s[t - o] : 0;
        __syncthreads();
        s[t] += a;
        __syncthreads();
    }
    if (t < nC) ofs[gb * nC + t] = baseE[g * (NB + 1) + b] + s[t] - v;
}

__global__ void k_p3(const int* __restrict__ e0, const int* __restrict__ e1,
                     const int* __restrict__ e2, const int* __restrict__ ofs,
                     unsigned* __restrict__ part, int E, int nC, int NB) {
    __shared__ int lbase[256];
    __shared__ int lcur[256];
    int g = blockIdx.x / nC, c = blockIdx.x - g * nC;
    const int* eg = (g == 0 ? e0 : g == 1 ? e1 : e2);
    const int* src = eg;
    const int* dst = eg + E;
    for (int b = threadIdx.x; b < NB; b += 256) {
        lbase[b] = ofs[((long)g * NB + b) * nC + c];
        lcur[b] = 0;
    }
    __syncthreads();
    int lo = c * CPE, hi = min(E, lo + CPE);
    unsigned* pg = part + (long)g * E;
    for (int e = lo + threadIdx.x; e < hi; e += 256) {
        int d = dst[e];
        int b = d >> 8;
        int pos = lbase[b] + atomicAdd(&lcur[b], 1);
        pg[pos] = ((unsigned)(d & 255) << 16) | (unsigned)src[e];
    }
}

__global__ void k_p4(const unsigned* __restrict__ part, const int* __restrict__ baseE,
                     int* __restrict__ rowptr, int* __restrict__ srcs,
                     int E, int N, int NB) {
    __shared__ int h[256];
    __shared__ int s[256];
    __shared__ int cur[256];
    int g = blockIdx.x / NB, b = blockIdx.x - g * NB;
    int n0 = b << 8;
    int nn = min(256, N - n0);
    int lo = baseE[g * (NB + 1) + b], hi = baseE[g * (NB + 1) + b + 1];
    int t = threadIdx.x;
    h[t] = 0;
    __syncthreads();
    const unsigned* pg = part + (long)g * E;
    for (int i = lo + t; i < hi; i += 256)
        atomicAdd(&h[pg[i] >> 16], 1);
    __syncthreads();
    int v = h[t];
    s[t] = v;
    __syncthreads();
    for (int o = 1; o < 256; o <<= 1) {
        int a = (t >= o) ? s[t - o] : 0;
        __syncthreads();
        s[t] += a;
        __syncthreads();
    }
    int excl = lo + s[t] - v;
    if (t < nn) rowptr[(long)g * (N + 1) + n0 + t] = excl;
    cur[t] = excl;
    __syncthreads();
    int* sg = srcs + (long)g * E;
    for (int i = lo + t; i < hi; i += 256) {
        unsigned r = pg[i];
        int pos = atomicAdd(&cur[r >> 16], 1);
        sg[pos] = (int)(r & 0xFFFFu);
    }
}

// ---------- generic MFMA GEMM core (L2/L3; 16 rows/wave) ----------
template <bool ABF, bool BN_IN, bool RELU_OUT, bool BF16_OUT>
__device__ __forceinline__ void gemm_body(const void* X, const float* stats,
                                          const u16* __restrict__ Wb,
                                          const float* __restrict__ bias,
                                          void* Yv, int MT, int Cin, int SH,
                                          int wl, int l) {
    int mt = wl >> SH;
    if (mt >= MT) return;
    int CG = 1 << SH;
    int COUT = CG * 64;
    int cg = wl & (CG - 1);
    int lm = l & 15, lh = l >> 4;
    int kb = lh * 8;

    const float* xrf = nullptr;
    const u16* xrb = nullptr;
    if (ABF) xrb = (const u16*)X + (long)(mt * 16 + lm) * Cin + kb;
    else     xrf = (const float*)X + (long)(mt * 16 + lm) * Cin + kb;
    const u16* wp[4];
#pragma unroll
    for (int t = 0; t < 4; ++t)
        wp[t] = Wb + (long)(cg * 64 + t * 16 + lm) * Cin + kb;
    const float* scp = nullptr;
    const float* shp = nullptr;
    if (BN_IN) {
        scp = stats + 2 * Cin + kb;
        shp = stats + 3 * Cin + kb;
    }

    f32x4 acc[4];
#pragma unroll
    for (int t = 0; t < 4; ++t) acc[t] = (f32x4){0.f, 0.f, 0.f, 0.f};

    for (int k0 = 0; k0 < Cin; k0 += 32) {
        short8 a;
        if (ABF) {
            short8 raw = *reinterpret_cast<const short8*>(xrb);
            if (BN_IN) {
#pragma unroll
                for (int j = 0; j < 8; ++j) {
                    float x = bf2f((u16)raw[j]);
                    x = fmaxf(fmaf(x, scp[j], shp[j]), 0.f);
                    a[j] = (short)f2bf(x);
                }
                scp += 32; shp += 32;
            } else {
                a = raw;
            }
            xrb += 32;
        } else {
            float4 x0 = *reinterpret_cast<const float4*>(xrf);
            float4 x1 = *reinterpret_cast<const float4*>(xrf + 4);
            a[0] = (short)f2bf(x0.x); a[1] = (short)f2bf(x0.y);
            a[2] = (short)f2bf(x0.z); a[3] = (short)f2bf(x0.w);
            a[4] = (short)f2bf(x1.x); a[5] = (short)f2bf(x1.y);
            a[6] = (short)f2bf(x1.z); a[7] = (short)f2bf(x1.w);
            xrf += 32;
        }
#pragma unroll
        for (int t = 0; t < 4; ++t) {
            short8 b = *reinterpret_cast<const short8*>(wp[t]);
            acc[t] = __builtin_amdgcn_mfma_f32_16x16x32_bf16(a, b, acc[t], 0, 0, 0);
            wp[t] += 32;
        }
    }

    int nb = mt * 16 + lh * 4;
#pragma unroll
    for (int t = 0; t < 4; ++t) {
        int col = cg * 64 + t * 16 + lm;
        float bi = bias[col];
#pragma unroll
        for (int r = 0; r < 4; ++r) {
            float v = acc[t][r] + bi;
            if (RELU_OUT) v = fmaxf(v, 0.f);
            if (BF16_OUT)
                ((u16*)Yv)[(long)(nb + r) * COUT + col] = f2bf(v);
            else
                ((float*)Yv)[(long)(nb + r) * COUT + col] = v;
        }
    }
}

// ---------- L1 GEMM m4: 64 rows x 64 cols per wave; B reused across 4 M-frags ----------
// Output: fp8 e4m3 (128 B/row) when FP8L1, else bf16. OOB: clamped loads, guarded stores.
__device__ __forceinline__ void gemmL1m4(const float* __restrict__ X,
                                         const u16* __restrict__ Wb,
                                         const float* __restrict__ bias,
                                         u16* __restrict__ Yb,
                                         int N, int Cin, int wl, int l) {
    int mt = wl >> 1;          // 64-row supertile
    int cg = wl & 1;           // 64-col half
    int m0 = mt * 64;
    if (m0 >= N) return;
    int lm = l & 15, lh = l >> 4;
    int kb = lh * 8;

    const u16* wp[4];
#pragma unroll
    for (int t = 0; t < 4; ++t)
        wp[t] = Wb + (long)(cg * 64 + t * 16 + lm) * Cin + kb;

    const float* xr[4];
#pragma unroll
    for (int mi = 0; mi < 4; ++mi) {
        int row = m0 + mi * 16 + lm;
        if (row >= N) row = N - 1;   // clamp: garbage lands only in unstored D rows
        xr[mi] = X + (long)row * Cin + kb;
    }

    f32x4 acc[4][4];
#pragma unroll
    for (int mi = 0; mi < 4; ++mi)
#pragma unroll
        for (int t = 0; t < 4; ++t) acc[mi][t] = (f32x4){0.f, 0.f, 0.f, 0.f};

    for (int k0 = 0; k0 < Cin; k0 += 32) {
        short8 b[4];
#pragma unroll
        for (int t = 0; t < 4; ++t) {
            b[t] = *reinterpret_cast<const short8*>(wp[t]);
            wp[t] += 32;
        }
        short8 a[4];
#pragma unroll
        for (int mi = 0; mi < 4; ++mi) {
            float4 x0 = *reinterpret_cast<const float4*>(xr[mi]);
            float4 x1 = *reinterpret_cast<const float4*>(xr[mi] + 4);
            xr[mi] += 32;
            a[mi][0] = (short)f2bf(x0.x); a[mi][1] = (short)f2bf(x0.y);
            a[mi][2] = (short)f2bf(x0.z); a[mi][3] = (short)f2bf(x0.w);
            a[mi][4] = (short)f2bf(x1.x); a[mi][5] = (short)f2bf(x1.y);
            a[mi][6] = (short)f2bf(x1.z); a[mi][7] = (short)f2bf(x1.w);
        }
#pragma unroll
        for (int mi = 0; mi < 4; ++mi)
#pragma unroll
            for (int t = 0; t < 4; ++t)
                acc[mi][t] = __builtin_amdgcn_mfma_f32_16x16x32_bf16(a[mi], b[t], acc[mi][t], 0, 0, 0);
    }

#pragma unroll
    for (int mi = 0; mi < 4; ++mi) {
        int nb = m0 + mi * 16 + lh * 4;
#pragma unroll
        for (int t = 0; t < 4; ++t) {
            int col = cg * 64 + t * 16 + lm;
            float bi = bias[col];
#if FP8L1
            float v0 = acc[mi][t][0] + bi, v1 = acc[mi][t][1] + bi;
            float v2 = acc[mi][t][2] + bi, v3 = acc[mi][t][3] + bi;
            int p01 = __builtin_amdgcn_cvt_pk_fp8_f32(v0, v1, 0, false);
            int p23 = __builtin_amdgcn_cvt_pk_fp8_f32(v2, v3, 0, false);
            u8* Y8 = reinterpret_cast<u8*>(Yb);
            if (nb + 0 < N) Y8[(long)(nb + 0) * 128 + col] = (u8)(p01 & 0xff);
            if (nb + 1 < N) Y8[(long)(nb + 1) * 128 + col] = (u8)((p01 >> 8) & 0xff);
            if (nb + 2 < N) Y8[(long)(nb + 2) * 128 + col] = (u8)(p23 & 0xff);
            if (nb + 3 < N) Y8[(long)(nb + 3) * 128 + col] = (u8)((p23 >> 8) & 0xff);
#else
#pragma unroll
            for (int r = 0; r < 4; ++r) {
                int row = nb + r;
                if (row < N)
                    Yb[(long)row * 128 + col] = f2bf(acc[mi][t][r] + bi);
            }
#endif
        }
    }
}

__global__ __launch_bounds__(256) void k_gemmL1(
        const float* x0, const float* x1, const float* x2,
        const u16* w0, const u16* w1, const u16* w2,
        const float* b0, const float* b1, const float* b2,
        u16* Yb, int N, int B1) {
    int g = blockIdx.x / B1;
    int wl = (blockIdx.x - g * B1) * 4 + (threadIdx.x >> 6);
    int l = threadIdx.x & 63;
    const float* x = g == 0 ? x0 : (g == 1 ? x1 : x2);
    const u16* w = g == 0 ? w0 : (g == 1 ? w1 : w2);
    const float* b = g == 0 ? b0 : (g == 1 ? b1 : b2);
    int cin = (g == 1) ? 128 : 256;
    gemmL1m4(x, w, b, Yb + (long)g * N * 128, N, cin, wl, l);
}

// L2: 3 graphs, A bf16 + BN_IN, shared weights, CG=1 (Cout 64), bf16 out
// output stride between graphs is N*64 (COUT=64) to match k_aggb3<64>.
__global__ __launch_bounds__(256) void k_gemmL2(
        const u16* Hb, const float* ST, const u16* wext, const float* bext,
        u16* Yb, int MT, int N, int B2) {
    int g = blockIdx.x / B2;
    int wl = (blockIdx.x - g * B2) * 4 + (threadIdx.x >> 6);
    gemm_body<true, true, false, true>(Hb + (long)g * N * 128, ST + g * 512, wext,
                                       bext, Yb + (long)g * N * 64, MT, 128, 0,
                                       wl, threadIdx.x & 63);
}

// L3: 2 graphs, A bf16, fp32 relu out; g0: CG=4 Cout256 -> f0, g1: CG=2 Cout128 -> f1
__global__ __launch_bounds__(256) void k_gemmL3(
        const u16* h3, const u16* wr0, const u16* wr1,
        const float* br0, const float* br1,
        float* f0, float* f1, int MT, int N, int B0) {
    int b = blockIdx.x;
    int g = (b < B0) ? 0 : 1;
    int wl = (g == 0 ? b : b - B0) * 4 + (threadIdx.x >> 6);
    if (g == 0)
        gemm_body<true, false, true, false>(h3, nullptr, wr0, br0, f0, MT, 64, 2,
                                            wl, threadIdx.x & 63);
    else
        gemm_body<true, false, true, false>(h3 + (long)N * 64, nullptr, wr1, br1,
                                            f1, MT, 64, 1, wl, threadIdx.x & 63);
}

// ---------- batched aggregation: out[n] = in[n] + sum_{e} in[src[e]] ----------
// CH=128: input fp8 (FP8L1) or bf16; output bf16. CH=64: bf16 in/out. fp32 accum.
template <int CH>
__global__ void k_aggb3(const u16* __restrict__ in, const int* __restrict__ rp,
                        const int* __restrict__ sr, u16* __restrict__ outb,
                        int N, int E, int BPG) {
    int g = blockIdx.x / BPG;
    int bb = blockIdx.x - g * BPG;
    int l = threadIdx.x & 63;
    int ll = l & 31;
    int n = (bb << 3) + ((threadIdx.x >> 6) << 1) + (l >> 5);
    if (n >= N) return;
    const int* rowptr = rp + (long)g * (N + 1);
    const int* srcs = sr + (long)g * E;
    int p = rowptr[n], p1 = rowptr[n + 1];
    if constexpr (CH == 128) {
#if FP8L1
        const unsigned* Yp = reinterpret_cast<const unsigned*>(in + (long)g * N * 128) + ll;
        unsigned a = Yp[(long)n << 5];
        f32x2 alo = __builtin_amdgcn_cvt_pk_f32_fp8(a, false);
        f32x2 ahi = __builtin_amdgcn_cvt_pk_f32_fp8(a, true);
        float s0 = alo[0], s1 = alo[1], s2 = ahi[0], s3 = ahi[1];
        while (p + 8 <= p1) {
            unsigned r[8];
#pragma unroll
            for (int j = 0; j < 8; ++j) r[j] = Yp[(long)srcs[p + j] << 5];
#pragma unroll
            for (int j = 0; j < 8; ++j) {
                f32x2 lo = __builtin_amdgcn_cvt_pk_f32_fp8(r[j], false);
                f32x2 hi = __builtin_amdgcn_cvt_pk_f32_fp8(r[j], true);
                s0 += lo[0]; s1 += lo[1]; s2 += hi[0]; s3 += hi[1];
            }
            p += 8;
        }
        while (p < p1) {
            unsigned r = Yp[(long)srcs[p] << 5];
            f32x2 lo = __builtin_amdgcn_cvt_pk_f32_fp8(r, false);
            f32x2 hi = __builtin_amdgcn_cvt_pk_f32_fp8(r, true);
            s0 += lo[0]; s1 += lo[1]; s2 += hi[0]; s3 += hi[1];
            ++p;
        }
#else
        const ushort4* Yp = reinterpret_cast<const ushort4*>(in + (long)g * N * 128) + ll;
        ushort4 a = Yp[(long)n << 5];
        float s0 = bf2f(a.x), s1 = bf2f(a.y), s2 = bf2f(a.z), s3 = bf2f(a.w);
        while (p + 8 <= p1) {
            ushort4 r[8];
#pragma unroll
            for (int j = 0; j < 8; ++j) r[j] = Yp[(long)srcs[p + j] << 5];
#pragma unroll
            for (int j = 0; j < 8; ++j) {
                s0 += bf2f(r[j].x); s1 += bf2f(r[j].y);
                s2 += bf2f(r[j].z); s3 += bf2f(r[j].w);
            }
            p += 8;
        }
        while (p < p1) {
            ushort4 r = Yp[(long)srcs[p] << 5];
            s0 += bf2f(r.x); s1 += bf2f(r.y); s2 += bf2f(r.z); s3 += bf2f(r.w);
            ++p;
        }
#endif
        ushort4 o = make_ushort4(f2bf(s0), f2bf(s1), f2bf(s2), f2bf(s3));
        (reinterpret_cast<ushort4*>(outb + (long)g * N * 128) + ll)[(long)n << 5] = o;
    } else {
        const unsigned* Yp = reinterpret_cast<const unsigned*>(in + (long)g * N * 64) + ll;
        unsigned a = Yp[(long)n << 5];
        float s0 = bf2f((u16)a), s1 = bf2f((u16)(a >> 16));
        while (p + 8 <= p1) {
            unsigned r[8];
#pragma unroll
            for (int j = 0; j < 8; ++j) r[j] = Yp[(long)srcs[p + j] << 5];
#pragma unroll
            for (int j = 0; j < 8; ++j) {
                s0 += bf2f((u16)r[j]);
                s1 += bf2f((u16)(r[j] >> 16));
            }
            p += 8;
        }
        while (p < p1) {
            unsigned r = Yp[(long)srcs[p] << 5];
            s0 += bf2f((u16)r);
            s1 += bf2f((u16)(r >> 16));
            ++p;
        }
        unsigned o = (unsigned)f2bf(s0) | ((unsigned)f2bf(s1) << 16);
        (reinterpret_cast<unsigned*>(outb + (long)g * N * 64) + ll)[(long)n << 5] = o;
    }
}

// ---------- BN stats (bf16 input), two-stage deterministic, batched ----------
template <int C>
__global__ void k_bnstats1(const u16* __restrict__ h, float* __restrict__ parts,
                           int N, int PSTRIDE) {
    constexpr int RPB = 256 / C;
    constexpr int LGC = (C == 128) ? 7 : 6;
    __shared__ float ts[256], ts2[256];
    int g = blockIdx.x >> 8;
    int blk = blockIdx.x & 255;
    const u16* hg = h + (long)g * N * C;
    float* pg = parts + (long)g * PSTRIDE;
    int tid = threadIdx.x;
    int c = tid & (C - 1);
    float s = 0.f, s2 = 0.f;
    for (int n = blk * RPB + (tid >> LGC); n < N; n += 256 * RPB) {
        float v = bf2f(hg[((long)n << LGC) + c]);
        s += v;
        s2 = fmaf(v, v, s2);
    }
    ts[tid] = s;
    ts2[tid] = s2;
    __syncthreads();
    if (tid < C) {
#pragma unroll
        for (int i = 1; i < RPB; ++i) {
            s += ts[tid + i * C];
            s2 += ts2[tid + i * C];
        }
        pg[blk * 2 * C + tid] = s;
        pg[blk * 2 * C + C + tid] = s2;
    }
}

template <int C>
__global__ void k_bnstats2(const float* __restrict__ parts,
                           const float* g0, const float* g1, const float* g2,
                           const float* b0, const float* b1, const float* b2,
                           float* __restrict__ ST, float invN, int PSTRIDE) {
    int g = blockIdx.x;
    const float* gam = g == 0 ? g0 : (g == 1 ? g1 : g2);
    const float* bet = g == 0 ? b0 : (g == 1 ? b1 : b2);
    const float* pg = parts + (long)g * PSTRIDE;
    float* st = ST + g * 4 * C;
    int c = threadIdx.x;
    float s = 0.f, s2 = 0.f;
    for (int b = 0; b < 256; ++b) {
        s += pg[b * 2 * C + c];
        s2 += pg[b * 2 * C + C + c];
    }
    float m = s * invN;
    float v = s2 * invN - m * m;
    float sc = gam[c] * rsqrtf(v + 1e-5f);
    st[2 * C + c] = sc;
    st[3 * C + c] = bet[c] - m * sc;
}

// ---------- batched BN apply (bf16 in, fp32 out + bf16 copy for g<2) ----------
__global__ void k_bnapply3(const u16* __restrict__ h2b, const float* __restrict__ ST2,
                           float* __restrict__ out, u16* __restrict__ obb,
                           int N, int BPG) {
    int g = blockIdx.x / BPG;
    int idx = (blockIdx.x - g * BPG) * 256 + threadIdx.x;
    if (idx >= N * 16) return;
    int n = idx >> 4;
    int c4 = (idx & 15) << 2;
    const u16* hg = h2b + (long)g * N * 64;
    const float* st = ST2 + g * 256;
    ushort4 hv = *reinterpret_cast<const ushort4*>(hg + ((long)n << 6) + c4);
    const float4 sc = *reinterpret_cast<const float4*>(st + 128 + c4);
    const float4 sh = *reinterpret_cast<const float4*>(st + 192 + c4);
    float4 o;
    o.x = fmaxf(fmaf(bf2f(hv.x), sc.x, sh.x), 0.f);
    o.y = fmaxf(fmaf(bf2f(hv.y), sc.y, sh.y), 0.f);
    o.z = fmaxf(fmaf(bf2f(hv.z), sc.z, sh.z), 0.f);
    o.w = fmaxf(fmaf(bf2f(hv.w), sc.w, sh.w), 0.f);
    // g0 -> o_h0 (out + N*64), g1 -> o_h1 (out + 2N*64), g2(s) -> o_hs (out)
    float* yb = (g == 0) ? out + (long)N * 64 : (g == 1) ? out + (long)N * 128 : out;
    *reinterpret_cast<float4*>(yb + ((long)n << 6) + c4) = o;
    if (g < 2) {
        ushort4 ob = make_ushort4(f2bf(o.x), f2bf(o.y), f2bf(o.z), f2bf(o.w));
        *reinterpret_cast<ushort4*>(obb + (long)g * N * 64 + ((long)n << 6) + c4) = ob;
    }
}

static inline int cdiv(long a, int b) { return (int)((a + b - 1) / b); }

extern "C" void kernel_launch(void* const* d_in, const int* in_sizes, int n_in,
                              void* d_out, int out_size, void* d_ws, size_t ws_size,
                              hipStream_t stream) {
    const float* ft0 = (const float*)d_in[0];
    const float* ft1 = (const float*)d_in[1];
    const float* fs  = (const float*)d_in[2];
    const int* et0 = (const int*)d_in[3];
    const int* et1 = (const int*)d_in[4];
    const int* es  = (const int*)d_in[5];
    const float* aT0_W = (const float*)d_in[6];
    const float* aT0_b = (const float*)d_in[7];
    const float* aT0_g = (const float*)d_in[8];
    const float* aT0_be = (const float*)d_in[9];
    const float* aT1_W = (const float*)d_in[10];
    const float* aT1_b = (const float*)d_in[11];
    const float* aT1_g = (const float*)d_in[12];
    const float* aT1_be = (const float*)d_in[13];
    const float* aS_W = (const float*)d_in[14];
    const float* aS_b = (const float*)d_in[15];
    const float* aS_g = (const float*)d_in[16];
    const float* aS_be = (const float*)d_in[17];
    const float* ext_W = (const float*)d_in[18];
    const float* ext_b = (const float*)d_in[19];
    const float* ext_g = (const float*)d_in[20];
    const float* ext_be = (const float*)d_in[21];
    const float* rT0_W = (const float*)d_in[22];
    const float* rT0_b = (const float*)d_in[23];
    const float* rT1_W = (const float*)d_in[24];
    const float* rT1_b = (const float*)d_in[25];

    const int N = in_sizes[0] / 256;
    const int E = in_sizes[3] / 2;
    const int NB = cdiv(N, 256);
    const int nC = cdiv(E, CPE);
    const int MT = N / 16;

    float* out = (float*)d_out;
    float* o_f0 = out + (long)N * 192;      // [N,256]
    float* o_f1 = out + (long)N * 448;      // [N,128]

    // workspace
    char* p = (char*)d_ws;
    auto align16 = [&]() { p = (char*)(((uintptr_t)p + 15) & ~(uintptr_t)15); };
    u16* Yb  = (u16*)p;        p += (size_t)3 * N * 128 * 2;   // L1 (fp8/bf16) / L2 gemm outputs
    u16* Hb  = (u16*)p;        p += (size_t)3 * N * 128 * 2;   // L1 pre-BN agg (bf16)
    u16* h2b = (u16*)p;        p += (size_t)3 * N * 64 * 2;    // L2 pre-BN agg / L3 agg
    u16* obb = (u16*)p;        p += (size_t)2 * N * 64 * 2;    // bf16 o_h0/o_h1
    int* rp   = (int*)p;       p += (size_t)3 * (N + 1) * 4;
    int* sr   = (int*)p;       p += (size_t)3 * E * 4;
    unsigned* part = (unsigned*)p; p += (size_t)3 * E * 4;
    int* cnt  = (int*)p;       p += (size_t)3 * NB * nC * 4;
    int* ofs  = (int*)p;       p += (size_t)3 * NB * nC * 4;
    int* tot  = (int*)p;       p += (size_t)3 * NB * 4;
    int* baseE = (int*)p;      p += (size_t)3 * (NB + 1) * 4;
    align16();
    u16* WBF = (u16*)p;        p += (size_t)(256*128 + 128*128 + 256*128 + 128*64 + 64*256 + 64*128) * 2;
    align16();
    float* ST1 = (float*)p;    p += (size_t)3 * 512 * 4;
    float* ST2 = (float*)p;    p += (size_t)3 * 256 * 4;
    float* PARTS = (float*)p;  p += (size_t)3 * 256 * 256 * 4;

    u16* aT0b = WBF;
    u16* aT1b = aT0b + 256 * 128;
    u16* aSb  = aT1b + 128 * 128;
    u16* extb = aSb + 256 * 128;
    u16* rT0b = extb + 128 * 64;
    u16* rT1b = rT0b + 64 * 256;

    // ---- CSR build ----
    k_p1<<<3 * nC, 256, 0, stream>>>(et0, et1, es, cnt, E, nC, NB);
    k_p2a<<<3 * NB, 256, 0, stream>>>(cnt, tot, nC);
    k_p2b<<<3, 256, 0, stream>>>(tot, baseE, rp, E, N, NB);
    k_p2c<<<3 * NB, 256, 0, stream>>>(cnt, baseE, ofs, nC, NB);
    k_p3<<<3 * nC, 256, 0, stream>>>(et0, et1, es, ofs, part, E, nC, NB);
    k_p4<<<3 * NB, 256, 0, stream>>>(part, baseE, rp, sr, E, N, NB);

    // ---- weight converts (one launch) ----
    {
        int tot_w = 256*128 + 128*128 + 256*128 + 128*64 + 64*256 + 64*128;
        k_wcvt6<<<cdiv(tot_w, 256), 256, 0, stream>>>(
            aT0_W, aT1_W, aS_W, ext_W, rT0_W, rT1_W, WBF,
            256*128, 128*128, 256*128, 128*64, 64*256, 64*128);
    }

    const int B1 = cdiv((long)cdiv(N, 64) * 2, 4);   // L1: 64-row supertile x 2 col-halves
    const int B2 = cdiv(MT, 4);
    const int BPG = N / 8;           // agg blocks per graph (N % 8 == 0)
    const int BPA = cdiv((long)N * 16, 256);  // bnapply blocks per graph

    // ---- layer 1 ----
    k_gemmL1<<<3 * B1, 256, 0, stream>>>(ft0, ft1, fs, aT0b, aT1b, aSb,
                                         aT0_b, aT1_b, aS_b, Yb, N, B1);
    k_aggb3<128><<<3 * BPG, 256, 0, stream>>>(Yb, rp, sr, Hb, N, E, BPG);
    k_bnstats1<128><<<3 * 256, 256, 0, stream>>>(Hb, PARTS, N, 256 * 256);
    k_bnstats2<128><<<3, 128, 0, stream>>>(PARTS, aT0_g, aT1_g, aS_g,
                                           aT0_be, aT1_be, aS_be, ST1, 1.0f / N, 256 * 256);

    // ---- layer 2 ----
    k_gemmL2<<<3 * B2, 256, 0, stream>>>(Hb, ST1, extb, ext_b, Yb, MT, N, B2);
    k_aggb3<64><<<3 * BPG, 256, 0, stream>>>(Yb, rp, sr, h2b, N, E, BPG);
    k_bnstats1<64><<<3 * 256, 256, 0, stream>>>(h2b, PARTS, N, 256 * 128);
    k_bnstats2<64><<<3, 64, 0, stream>>>(PARTS, ext_g, ext_g, ext_g,
                                         ext_be, ext_be, ext_be, ST2, 1.0f / N, 256 * 128);
    k_bnapply3<<<3 * BPA, 256, 0, stream>>>(h2b, ST2, out, obb, N, BPA);

    // ---- layer 3 ----
    k_aggb3<64><<<2 * BPG, 256, 0, stream>>>(obb, rp, sr, h2b, N, E, BPG);
    k_gemmL3<<<MT + cdiv((long)MT * 2, 4), 256, 0, stream>>>(
        h2b, rT0b, rT1b, rT0_b, rT1_b, o_f0, o_f1, MT, N, MT);
}